// Round 3
// baseline (1133.021 us; speedup 1.0000x reference)
//
#include <hip/hip_runtime.h>

typedef unsigned short u16;
typedef __attribute__((ext_vector_type(4))) float f4;
typedef __attribute__((ext_vector_type(8))) __bf16 bf16x8;
typedef __attribute__((ext_vector_type(4))) float f32x4;

#define D_MODEL 2048
#define D_SSM 4096
#define D_STATE 128
#define NHEADS 64
#define HEADDIM 64
#define CHUNK 64
#define LTOT 4096
#define NB 2
#define CONV_DIM 4352
#define XBC_LD 4480   // 4352 conv channels + 64 dt + 64 pad
#define LOG2E 1.4426950408889634f

__device__ inline float bf2f(unsigned v) { return __uint_as_float(v << 16); }
__device__ inline u16 f2bf(float f) {
    unsigned u = __float_as_uint(f);
    unsigned r = (u + 0x7fffu + ((u >> 16) & 1u)) >> 16;
    return (u16)r;
}
__device__ inline unsigned pack2(float a, float b) {
    return (unsigned)f2bf(a) | ((unsigned)f2bf(b) << 16);
}
// raw v_exp_f32: input in log2 domain
__device__ inline float fexp2(float x) {
    float r;
    asm("v_exp_f32 %0, %1" : "=v"(r) : "v"(x));
    return r;
}
// packed f32x2 -> bf16x2 (RNE), one instruction
__device__ inline unsigned cvtpk(float lo, float hi) {
    unsigned r;
    asm("v_cvt_pk_bf16_f32 %0, %1, %2" : "=v"(r) : "v"(lo), "v"(hi));
    return r;
}
__device__ inline void gload_lds16(const void* g, void* l) {
    __builtin_amdgcn_global_load_lds((const __attribute__((address_space(1))) void*)g,
                                     (__attribute__((address_space(3))) void*)l, 16, 0, 0);
}

// ---------------- f32 -> bf16 cast ----------------
__global__ __launch_bounds__(256) void tobf16_kernel(const float* __restrict__ src,
                                                     u16* __restrict__ dst, int n4) {
    int i = blockIdx.x * 256 + threadIdx.x;
    if (i < n4) {
        f4 v = ((const f4*)src)[i];
        uint2 pk;
        pk.x = pack2(v[0], v[1]);
        pk.y = pack2(v[2], v[3]);
        ((uint2*)dst)[i] = pk;
    }
}

// W_in (8512 x 2048) f32 -> win_bf (8576 x 2048) bf16, pad rows zero
__global__ __launch_bounds__(256) void winpad_kernel(const float* __restrict__ src,
                                                     u16* __restrict__ dst) {
    int i = blockIdx.x * 256 + threadIdx.x;
    if (i >= (8576 * 2048 / 4)) return;
    int col4 = i & 511;
    int row = i >> 9;
    f4 v = {0.f, 0.f, 0.f, 0.f};
    if (row < 8512) v = ((const f4*)src)[row * 512 + col4];
    uint2 pk;
    pk.x = pack2(v[0], v[1]);
    pk.y = pack2(v[2], v[3]);
    ((uint2*)dst)[i] = pk;
}

// ---------------- GEMM: C[m,n] = sum_k A[m,k]*B[n,k]; bf16 in; f32 or bf16 out ----
template <int OUT_BF16>
__global__ __launch_bounds__(256) void gemm_bt(const u16* __restrict__ A,
                                               const u16* __restrict__ B,
                                               void* __restrict__ Cp, int K, int ldC) {
    __shared__ u16 As[128 * 32];
    __shared__ u16 Bsm[128 * 32];
    int t = threadIdx.x, w = t >> 6, lane = t & 63;
    int blockM = blockIdx.y * 128, blockN = blockIdx.x * 128;
    int wm = (w & 1) * 64, wn = (w >> 1) * 64;

    const u16* Ab = A + (size_t)(blockM + 32 * w + (lane >> 2)) * K + (lane & 3) * 8;
    const u16* Bb = B + (size_t)(blockN + 32 * w + (lane >> 2)) * K + (lane & 3) * 8;
    u16* AsW = As + w * 1024;
    u16* BsW = Bsm + w * 1024;

    f32x4 acc[4][4] = {};
    const bf16x8* As8 = (const bf16x8*)As;
    const bf16x8* Bs8 = (const bf16x8*)Bsm;
    int aoff = (wm + (lane & 15)) * 4 + (lane >> 4);
    int boff = (wn + (lane & 15)) * 4 + (lane >> 4);

    for (int k0 = 0; k0 < K; k0 += 32) {
        const u16* Ag = Ab + k0;
        const u16* Bg = Bb + k0;
        gload_lds16(Ag, AsW);
        gload_lds16(Ag + (size_t)16 * K, AsW + 512);
        gload_lds16(Bg, BsW);
        gload_lds16(Bg + (size_t)16 * K, BsW + 512);
        __syncthreads();
        bf16x8 af[4], bfv[4];
#pragma unroll
        for (int i = 0; i < 4; i++) af[i] = As8[aoff + 64 * i];
#pragma unroll
        for (int j = 0; j < 4; j++) bfv[j] = Bs8[boff + 64 * j];
#pragma unroll
        for (int i = 0; i < 4; i++)
#pragma unroll
            for (int j = 0; j < 4; j++)
                acc[i][j] = __builtin_amdgcn_mfma_f32_16x16x32_bf16(af[i], bfv[j], acc[i][j], 0, 0, 0);
        __syncthreads();
    }
    int rbase = blockM + wm + (lane >> 4) * 4;
    int cbase = blockN + wn + (lane & 15);
    if (OUT_BF16) {
        u16* C = (u16*)Cp;
#pragma unroll
        for (int i = 0; i < 4; i++)
#pragma unroll
            for (int j = 0; j < 4; j++)
#pragma unroll
                for (int r = 0; r < 4; r++)
                    C[(size_t)(rbase + 16 * i + r) * ldC + cbase + 16 * j] = f2bf(acc[i][j][r]);
    } else {
        float* C = (float*)Cp;
#pragma unroll
        for (int i = 0; i < 4; i++)
#pragma unroll
            for (int j = 0; j < 4; j++)
#pragma unroll
                for (int r = 0; r < 4; r++)
                    C[(size_t)(rbase + 16 * i + r) * ldC + cbase + 16 * j] = acc[i][j][r];
    }
}

// ---------------- depthwise causal conv(4) + bias + silu; bf16 in/out ----------------
__global__ __launch_bounds__(256) void conv_kernel(const u16* __restrict__ xbcdt,
                                                   const float* __restrict__ conv_w,
                                                   const float* __restrict__ conv_b,
                                                   u16* __restrict__ convO) {
    int ch = blockIdx.x * 256 + threadIdx.x;  // 17*256 = 4352 exact
    int row = blockIdx.y;                     // 8192
    int l = row & (LTOT - 1);
    f4 w = *(const f4*)&conv_w[ch * 4];
    float acc = conv_b[ch];
#pragma unroll
    for (int k = 0; k < 4; ++k) {
        int ls = l - 3 + k;
        if (ls >= 0) acc += bf2f(xbcdt[(size_t)(row - 3 + k) * XBC_LD + ch]) * w[k];
    }
    convO[(size_t)row * CONV_DIM + ch] = f2bf(acc / (1.f + __expf(-acc)));
}

// ---------------- dt = softplus(raw + bias) -> dtp[row][h] f32 ----------------
__global__ __launch_bounds__(256) void dt_kernel(const u16* __restrict__ xbcdt,
                                                 const float* __restrict__ dt_bias,
                                                 float* __restrict__ dtp) {
    int idx = blockIdx.x * 256 + threadIdx.x;
    if (idx >= NB * LTOT * NHEADS) return;
    int row = idx >> 6, h = idx & 63;
    float x = bf2f(xbcdt[(size_t)row * XBC_LD + CONV_DIM + h]) + dt_bias[h];
    dtp[idx] = (x > 15.f) ? x : log1pf(__expf(x));
}

// ---------------- CB[l,s] = sum_n C[l,n]*B[s,n] per (b,c) -> CBb f32 ----------------
__global__ __launch_bounds__(256) void cb_kernel(const u16* __restrict__ convO,
                                                 float* __restrict__ CBb) {
    __shared__ u16 Bt[128 * 68];  // [n][s]
    __shared__ u16 Ct[128 * 68];  // [n][l]
    int bc = blockIdx.x;
    int c = bc & 63, b = bc >> 6;
    int rowbase = b * LTOT + c * CHUNK;
    int t = threadIdx.x;
#pragma unroll
    for (int i = 0; i < 32; i++) {
        int idx = i * 256 + t;
        int s = idx >> 7, n = idx & 127;
        Bt[n * 68 + s] = convO[(size_t)(rowbase + s) * CONV_DIM + D_SSM + n];
        Ct[n * 68 + s] = convO[(size_t)(rowbase + s) * CONV_DIM + D_SSM + D_STATE + n];
    }
    __syncthreads();
    int sq = t & 15, lq = t >> 4;
    f4 acc[4] = {};
#pragma unroll 4
    for (int n = 0; n < 128; n++) {
        ushort4 bv = *(const ushort4*)&Bt[n * 68 + sq * 4];
        ushort4 cv = *(const ushort4*)&Ct[n * 68 + lq * 4];
        f4 bf;
        bf[0] = bf2f(bv.x); bf[1] = bf2f(bv.y); bf[2] = bf2f(bv.z); bf[3] = bf2f(bv.w);
        float c0 = bf2f(cv.x), c1 = bf2f(cv.y), c2 = bf2f(cv.z), c3 = bf2f(cv.w);
        acc[0] += c0 * bf; acc[1] += c1 * bf; acc[2] += c2 * bf; acc[3] += c3 * bf;
    }
    float* outb = CBb + (size_t)bc * 4096;
#pragma unroll
    for (int j = 0; j < 4; j++) *(f4*)&outb[(lq * 4 + j) * 64 + sq * 4] = acc[j];
}

// ---------------- fused SSM (deep-prefetch pipeline, low-issue-count version) -------
// grid 512 = (b 2) x (h 64) x (pg 4); block 256 (4 waves); sequential over 64 chunks.
// This round: BT stored [n][64] with 16B-block XOR swizzle (block(l>>3)^=n&7) and
// quad-packed b64 writes (8 instead of 32 b16); x read once (2 b128) and reused by
// Y_diag + state update; log2-domain scan (raw v_exp_f32); v_cvt_pk_bf16_f32 packing.
__global__ __launch_bounds__(256, 2) void ssm_mfma(const u16* __restrict__ convO,
                                                   const float* __restrict__ dtp,
                                                   const float* __restrict__ CBb,
                                                   const float* __restrict__ A_log,
                                                   const float* __restrict__ Dvec,
                                                   u16* __restrict__ ybf) {
    __shared__ __align__(16) u16 xT[2][16 * 72];    // [p'][l]
    __shared__ __align__(16) u16 BT[2][128 * 64];   // [n][l swizzled 16B blocks]
    __shared__ __align__(16) u16 Sd[2][16 * 136];   // [p'][n]
    __shared__ __align__(16) float scal[2][256];    // dts | acs(log2) | wls | els

    int t = threadIdx.x;
    int w = t >> 6, lane = t & 63;
    int z = blockIdx.x;
    int pg = z & 3, h = (z >> 2) & 63, b = z >> 8;
    int pbase = h * 64 + pg * 16;
    float Ah2 = -__expf(A_log[h]) * LOG2E;  // log2-domain decay rate
    float Dh = Dvec[h];

    int fm = lane & 15;        // within-tile row/col index
    int fq = lane >> 4;        // quad 0..3
    int fk = fq * 8;           // k-base within a 32-wide k-step
    int sl = t & 63;           // xT staging: row l
    int sq = t >> 6;           // xT staging: quarter
    int lq = t & 15;           // BT staging: l-quad (rows 4lq..4lq+3)
    int no = t >> 4;           // BT staging: n-octet (cols no*8..no*8+7)

    f32x4 sacc[2] = {};        // state acc: element (p' = fq*4+r, n = 32w+16nt+fm)

    const float* CBbase = CBb + (size_t)(b * 64) * 4096;
    int yl = 16 * w + fm;      // A-operand row l for Y mfmas
    int btc0 = (32 * w + fm) * 64;          // BT col base, nt=0
    int fm7 = fm & 7;

    // ---------- prologue: stage chunk 0 into buffers[0]; load operands for chunk 0 ----
    bf16x8 afr[4];             // C rows for current chunk (loaded one iter ahead)
    f4 cbr[2][2];              // CB rows for current chunk
    {
        int rowbase = b * LTOT;
        const u16* rowp = convO + (size_t)rowbase * CONV_DIM;
        const u16* Cg = rowp + (size_t)yl * CONV_DIM + D_SSM + D_STATE;
#pragma unroll
        for (int kk = 0; kk < 4; ++kk) afr[kk] = *(const bf16x8*)(Cg + kk * 32 + fk);
        const float* CBrow = CBbase + yl * 64;
#pragma unroll
        for (int kk = 0; kk < 2; ++kk) {
            cbr[kk][0] = *(const f4*)&CBrow[kk * 32 + fk];
            cbr[kk][1] = *(const f4*)&CBrow[kk * 32 + fk + 4];
        }
        if (t < 64) {
            float dtv = dtp[(size_t)(rowbase + t) * 64 + h];
            float v = dtv * Ah2;
#pragma unroll
            for (int off = 1; off < 64; off <<= 1) {
                float pv = __shfl_up(v, off, 64);
                if (t >= off) v += pv;
            }
            float alast = __shfl(v, 63, 64);
            scal[0][t] = dtv;
            scal[0][64 + t] = v;
            scal[0][128 + t] = dtv * fexp2(alast - v);
            scal[0][192 + t] = fexp2(v);
        }
        ushort4 xv = *(const ushort4*)(rowp + (size_t)sl * CONV_DIM + pbase + sq * 4);
        xT[0][(sq * 4 + 0) * 72 + sl] = xv.x;
        xT[0][(sq * 4 + 1) * 72 + sl] = xv.y;
        xT[0][(sq * 4 + 2) * 72 + sl] = xv.z;
        xT[0][(sq * 4 + 3) * 72 + sl] = xv.w;
        {   // BT[0] staging, new layout
            const u16* bp = rowp + D_SSM + no * 8;
            union { uint4 v; unsigned ww[4]; } q[4];
#pragma unroll
            for (int r = 0; r < 4; ++r) q[r].v = *(const uint4*)(bp + (size_t)(4 * lq + r) * CONV_DIM);
            int base = no * 512 + (lq & 1) * 4;
            int lqh = lq >> 1;
#pragma unroll
            for (int j = 0; j < 8; ++j) {
                unsigned sel = (j & 1) ? 0x07060302u : 0x05040100u;
                uint2 pk;
                pk.x = __builtin_amdgcn_perm(q[1].ww[j >> 1], q[0].ww[j >> 1], sel);
                pk.y = __builtin_amdgcn_perm(q[3].ww[j >> 1], q[2].ww[j >> 1], sel);
                *(uint2*)&BT[0][base + j * 64 + ((lqh ^ j) << 3)] = pk;
            }
        }
#pragma unroll
        for (int nt = 0; nt < 2; ++nt)
#pragma unroll
            for (int r = 0; r < 4; ++r)
                Sd[0][(fq * 4 + r) * 136 + 32 * w + 16 * nt + fm] = 0;
        __syncthreads();
    }

    f4 ydef = {0.f, 0.f, 0.f, 0.f};   // deferred y values for chunk c-1
    int cur = 0;
    for (int c = 0; c < 64; ++c, cur ^= 1) {
        int rowbase = b * LTOT + c * CHUNK;
        const u16* rowp = convO + (size_t)rowbase * CONV_DIM;

        // ---- deferred y store for chunk c-1 ----
        if (c > 0) {
            unsigned y01 = cvtpk(ydef[0], ydef[1]);
            unsigned y23 = cvtpk(ydef[2], ydef[3]);
            u16* yp = ybf + (size_t)(rowbase - CHUNK + 16 * w + fq * 4) * D_SSM + pbase + fm;
            yp[0] = (u16)y01;
            yp[D_SSM] = (u16)(y01 >> 16);
            yp[2 * D_SSM] = (u16)y23;
            yp[3 * D_SSM] = (u16)(y23 >> 16);
        }

        // ---- next-chunk prefetch (C, CB rows; B-tile; x-tile; dt) ----
        bf16x8 afr_n[4] = {};
        f4 cbr_n[2][2] = {};
        uint4 bv0 = {}, bv1 = {}, bv2 = {}, bv3 = {};
        ushort4 xv = {0, 0, 0, 0};
        float dtv = 0.f;
        if (c < 63) {
            const u16* rowp1 = rowp + (size_t)CHUNK * CONV_DIM;
            const u16* Cg = rowp1 + (size_t)yl * CONV_DIM + D_SSM + D_STATE;
#pragma unroll
            for (int kk = 0; kk < 4; ++kk) afr_n[kk] = *(const bf16x8*)(Cg + kk * 32 + fk);
            const float* CBrow = CBbase + (size_t)(c + 1) * 4096 + yl * 64;
#pragma unroll
            for (int kk = 0; kk < 2; ++kk) {
                cbr_n[kk][0] = *(const f4*)&CBrow[kk * 32 + fk];
                cbr_n[kk][1] = *(const f4*)&CBrow[kk * 32 + fk + 4];
            }
            const u16* bp = rowp1 + D_SSM + no * 8;
            bv0 = *(const uint4*)(bp + (size_t)(4 * lq + 0) * CONV_DIM);
            bv1 = *(const uint4*)(bp + (size_t)(4 * lq + 1) * CONV_DIM);
            bv2 = *(const uint4*)(bp + (size_t)(4 * lq + 2) * CONV_DIM);
            bv3 = *(const uint4*)(bp + (size_t)(4 * lq + 3) * CONV_DIM);
            xv = *(const ushort4*)(rowp1 + (size_t)sl * CONV_DIM + pbase + sq * 4);
            if (t < 64) dtv = dtp[(size_t)(rowbase + CHUNK + t) * 64 + h];
        }

        const float* sc = scal[cur];
        const u16* xTc = xT[cur];
        const u16* BTc = BT[cur];
        const u16* Sdc = Sd[cur];

        // ---- LDS register loads (issued together, consumed below) ----
        union { uint4 v; u16 us[8]; bf16x8 bv; } xx0, xx1;
        xx0.v = *(const uint4*)&xTc[fm * 72 + fk];
        xx1.v = *(const uint4*)&xTc[fm * 72 + 32 + fk];
        ushort4 xe = *(const ushort4*)&xTc[fm * 72 + 16 * w + fq * 4];
        f4 els4 = *(const f4*)&sc[192 + 16 * w + fq * 4];
        float acl = sc[64 + yl];
        float cd = sc[192 + 63];
        f4 ac00 = *(const f4*)&sc[64 + fk], ac01 = *(const f4*)&sc[64 + fk + 4];
        f4 ac10 = *(const f4*)&sc[96 + fk], ac11 = *(const f4*)&sc[96 + fk + 4];
        f4 dt00 = *(const f4*)&sc[fk], dt01 = *(const f4*)&sc[fk + 4];
        f4 dt10 = *(const f4*)&sc[32 + fk], dt11 = *(const f4*)&sc[32 + fk + 4];
        f4 w00 = *(const f4*)&sc[128 + fk], w01 = *(const f4*)&sc[128 + fk + 4];
        f4 w10 = *(const f4*)&sc[160 + fk], w11 = *(const f4*)&sc[160 + fk + 4];
        bf16x8 sdf0 = *(const bf16x8*)&Sdc[fm * 136 + fk];
        bf16x8 sdf1 = *(const bf16x8*)&Sdc[fm * 136 + 32 + fk];
        bf16x8 sdf2 = *(const bf16x8*)&Sdc[fm * 136 + 64 + fk];
        bf16x8 sdf3 = *(const bf16x8*)&Sdc[fm * 136 + 96 + fk];
        int pb0 = (fq ^ fm7) << 3;
        int pb1 = ((4 + fq) ^ fm7) << 3;
        bf16x8 btf00 = *(const bf16x8*)&BTc[btc0 + pb0];
        bf16x8 btf01 = *(const bf16x8*)&BTc[btc0 + 1024 + pb0];
        bf16x8 btf10 = *(const bf16x8*)&BTc[btc0 + pb1];
        bf16x8 btf11 = *(const bf16x8*)&BTc[btc0 + 1024 + pb1];

        // ---- Y_diag = G . x (independent VALU-heavy work first) ----
        f32x4 ydia = {0.f, 0.f, 0.f, 0.f};
        {
            union { unsigned u[4]; bf16x8 v; } gu;
            float g[8];
#pragma unroll
            for (int j = 0; j < 4; ++j) {
                int s = fk + j;
                g[j] = (s <= yl) ? cbr[0][0][j] * fexp2(acl - ac00[j]) * dt00[j] : 0.f;
            }
#pragma unroll
            for (int j = 0; j < 4; ++j) {
                int s = fk + 4 + j;
                g[4 + j] = (s <= yl) ? cbr[0][1][j] * fexp2(acl - ac01[j]) * dt01[j] : 0.f;
            }
            gu.u[0] = cvtpk(g[0], g[1]);
            gu.u[1] = cvtpk(g[2], g[3]);
            gu.u[2] = cvtpk(g[4], g[5]);
            gu.u[3] = cvtpk(g[6], g[7]);
            ydia = __builtin_amdgcn_mfma_f32_16x16x32_bf16(gu.v, xx0.bv, ydia, 0, 0, 0);
#pragma unroll
            for (int j = 0; j < 4; ++j) {
                int s = 32 + fk + j;
                g[j] = (s <= yl) ? cbr[1][0][j] * fexp2(acl - ac10[j]) * dt10[j] : 0.f;
            }
#pragma unroll
            for (int j = 0; j < 4; ++j) {
                int s = 32 + fk + 4 + j;
                g[4 + j] = (s <= yl) ? cbr[1][1][j] * fexp2(acl - ac11[j]) * dt11[j] : 0.f;
            }
            gu.u[0] = cvtpk(g[0], g[1]);
            gu.u[1] = cvtpk(g[2], g[3]);
            gu.u[2] = cvtpk(g[4], g[5]);
            gu.u[3] = cvtpk(g[6], g[7]);
            ydia = __builtin_amdgcn_mfma_f32_16x16x32_bf16(gu.v, xx1.bv, ydia, 0, 0, 0);
        }

        // ---- state update: S = cd*S + (w.x)^T . B ----
        sacc[0] *= cd;
        sacc[1] *= cd;
        {
            union { unsigned u[4]; bf16x8 v; } au;
            float xf[8];
#pragma unroll
            for (int j = 0; j < 8; ++j) xf[j] = bf2f(xx0.us[j]);
            au.u[0] = cvtpk(xf[0] * w00[0], xf[1] * w00[1]);
            au.u[1] = cvtpk(xf[2] * w00[2], xf[3] * w00[3]);
            au.u[2] = cvtpk(xf[4] * w01[0], xf[5] * w01[1]);
            au.u[3] = cvtpk(xf[6] * w01[2], xf[7] * w01[3]);
            sacc[0] = __builtin_amdgcn_mfma_f32_16x16x32_bf16(au.v, btf00, sacc[0], 0, 0, 0);
            sacc[1] = __builtin_amdgcn_mfma_f32_16x16x32_bf16(au.v, btf01, sacc[1], 0, 0, 0);
#pragma unroll
            for (int j = 0; j < 8; ++j) xf[j] = bf2f(xx1.us[j]);
            au.u[0] = cvtpk(xf[0] * w10[0], xf[1] * w10[1]);
            au.u[1] = cvtpk(xf[2] * w10[2], xf[3] * w10[3]);
            au.u[2] = cvtpk(xf[4] * w11[0], xf[5] * w11[1]);
            au.u[3] = cvtpk(xf[6] * w11[2], xf[7] * w11[3]);
            sacc[0] = __builtin_amdgcn_mfma_f32_16x16x32_bf16(au.v, btf10, sacc[0], 0, 0, 0);
            sacc[1] = __builtin_amdgcn_mfma_f32_16x16x32_bf16(au.v, btf11, sacc[1], 0, 0, 0);
        }

        // ---- Y_off = C . S^T ----
        f32x4 yoff = {0.f, 0.f, 0.f, 0.f};
        yoff = __builtin_amdgcn_mfma_f32_16x16x32_bf16(afr[0], sdf0, yoff, 0, 0, 0);
        yoff = __builtin_amdgcn_mfma_f32_16x16x32_bf16(afr[1], sdf1, yoff, 0, 0, 0);
        yoff = __builtin_amdgcn_mfma_f32_16x16x32_bf16(afr[2], sdf2, yoff, 0, 0, 0);
        yoff = __builtin_amdgcn_mfma_f32_16x16x32_bf16(afr[3], sdf3, yoff, 0, 0, 0);

        // ---- combine: y = yoff*exp(acum) + ydia + D*x ----
        {
            float xf0 = bf2f(xe.x), xf1 = bf2f(xe.y), xf2 = bf2f(xe.z), xf3 = bf2f(xe.w);
            ydef[0] = yoff[0] * els4[0] + ydia[0] + Dh * xf0;
            ydef[1] = yoff[1] * els4[1] + ydia[1] + Dh * xf1;
            ydef[2] = yoff[2] * els4[2] + ydia[2] + Dh * xf2;
            ydef[3] = yoff[3] * els4[3] + ydia[3] + Dh * xf3;
        }

        // ---- write phase: stage chunk c+1 into buffers[nxt] ----
        if (c < 63) {
            int nxt = cur ^ 1;
            if (t < 64) {
                float v = dtv * Ah2;
#pragma unroll
                for (int off = 1; off < 64; off <<= 1) {
                    float pv = __shfl_up(v, off, 64);
                    if (t >= off) v += pv;
                }
                float alast = __shfl(v, 63, 64);
                scal[nxt][t] = dtv;
                scal[nxt][64 + t] = v;
                scal[nxt][128 + t] = dtv * fexp2(alast - v);
                scal[nxt][192 + t] = fexp2(v);
            }
            xT[nxt][(sq * 4 + 0) * 72 + sl] = xv.x;
            xT[nxt][(sq * 4 + 1) * 72 + sl] = xv.y;
            xT[nxt][(sq * 4 + 2) * 72 + sl] = xv.z;
            xT[nxt][(sq * 4 + 3) * 72 + sl] = xv.w;
            {
                union { uint4 v; unsigned ww[4]; } q0, q1, q2, q3;
                q0.v = bv0; q1.v = bv1; q2.v = bv2; q3.v = bv3;
                int base = no * 512 + (lq & 1) * 4;
                int lqh = lq >> 1;
#pragma unroll
                for (int j = 0; j < 8; ++j) {
                    unsigned sel = (j & 1) ? 0x07060302u : 0x05040100u;
                    uint2 pk;
                    pk.x = __builtin_amdgcn_perm(q1.ww[j >> 1], q0.ww[j >> 1], sel);
                    pk.y = __builtin_amdgcn_perm(q3.ww[j >> 1], q2.ww[j >> 1], sel);
                    *(uint2*)&BT[nxt][base + j * 64 + ((lqh ^ j) << 3)] = pk;
                }
            }
#pragma unroll
            for (int nt = 0; nt < 2; ++nt) {
                unsigned p01 = cvtpk(sacc[nt][0], sacc[nt][1]);
                unsigned p23 = cvtpk(sacc[nt][2], sacc[nt][3]);
                int colb = 32 * w + 16 * nt + fm;
                Sd[nxt][(fq * 4 + 0) * 136 + colb] = (u16)p01;
                Sd[nxt][(fq * 4 + 1) * 136 + colb] = (u16)(p01 >> 16);
                Sd[nxt][(fq * 4 + 2) * 136 + colb] = (u16)p23;
                Sd[nxt][(fq * 4 + 3) * 136 + colb] = (u16)(p23 >> 16);
            }
        }
        __syncthreads();

        // rotate prefetched operands into the "current" slots
#pragma unroll
        for (int kk = 0; kk < 4; ++kk) afr[kk] = afr_n[kk];
#pragma unroll
        for (int kk = 0; kk < 2; ++kk) {
            cbr[kk][0] = cbr_n[kk][0];
            cbr[kk][1] = cbr_n[kk][1];
        }
    }

    // final deferred y store (chunk 63)
    {
        unsigned y01 = cvtpk(ydef[0], ydef[1]);
        unsigned y23 = cvtpk(ydef[2], ydef[3]);
        u16* yp = ybf + (size_t)(b * LTOT + 63 * CHUNK + 16 * w + fq * 4) * D_SSM + pbase + fm;
        yp[0] = (u16)y01;
        yp[D_SSM] = (u16)(y01 >> 16);
        yp[2 * D_SSM] = (u16)y23;
        yp[3 * D_SSM] = (u16)(y23 >> 16);
    }
}

// ---------------- gate (silu(z)) + RMSNorm, in-place on y_bf ----------------
__global__ __launch_bounds__(256) void gate_norm(const u16* __restrict__ zbf,
                                                 const float* __restrict__ normw,
                                                 u16* __restrict__ ybf) {
    int row = blockIdx.x, t = threadIdx.x;
    const uint2* y2 = (const uint2*)(ybf + (size_t)row * D_SSM);
    const uint2* z2 = (const uint2*)(zbf + (size_t)row * D_SSM);
    f4 yg[4];
    float ss = 0.f;
#pragma unroll
    for (int i = 0; i < 4; ++i) {
        int idx = i * 256 + t;
        uint2 yv = y2[idx], zv = z2[idx];
        float ya[4] = {bf2f(yv.x & 0xffffu), bf2f(yv.x >> 16), bf2f(yv.y & 0xffffu), bf2f(yv.y >> 16)};
        float za[4] = {bf2f(zv.x & 0xffffu), bf2f(zv.x >> 16), bf2f(zv.y & 0xffffu), bf2f(zv.y >> 16)};
        f4 g;
#pragma unroll
        for (int k = 0; k < 4; ++k) {
            float sz = za[k] / (1.f + __expf(-za[k]));
            g[k] = ya[k] * sz;
            ss += g[k] * g[k];
        }
        yg[i] = g;
    }
#pragma unroll
    for (int off = 32; off; off >>= 1) ss += __shfl_down(ss, off, 64);
    __shared__ float red[4];
    if ((t & 63) == 0) red[t >> 6] = ss;
    __syncthreads();
    float tot = red[0] + red[1] + red[2] + red[3];
    float scale = rsqrtf(tot / (float)D_SSM + 1e-5f);
    const f4* nw4 = (const f4*)normw;
    uint2* out = (uint2*)(ybf + (size_t)row * D_SSM);
#pragma unroll
    for (int i = 0; i < 4; ++i) {
        int idx = i * 256 + t;
        f4 v = yg[i] * scale * nw4[idx];
        uint2 pk;
        pk.x = pack2(v[0], v[1]);
        pk.y = pack2(v[2], v[3]);
        out[idx] = pk;
    }
}

// ---------------- launch ----------------
extern "C" void kernel_launch(void* const* d_in, const int* in_sizes, int n_in,
                              void* d_out, int out_size, void* d_ws, size_t ws_size,
                              hipStream_t stream) {
    const float* u = (const float*)d_in[0];
    const float* W_in = (const float*)d_in[1];
    const float* conv_w = (const float*)d_in[2];
    const float* conv_b = (const float*)d_in[3];
    const float* dt_bias = (const float*)d_in[4];
    const float* A_log = (const float*)d_in[5];
    const float* Dv = (const float*)d_in[6];
    const float* normw = (const float*)d_in[7];
    const float* W_out = (const float*)d_in[8];
    float* out = (float*)d_out;
    char* ws = (char*)d_ws;

    // workspace layout (total 216,006,656 B ~= 206 MiB)
    u16* z_bf = (u16*)(ws + 0ULL);              //  8192x4096 bf16 = 67,108,864
    u16* xbcdt = (u16*)(ws + 67108864ULL);      //  8192x4480 bf16 = 73,400,320
    u16* y_bf = xbcdt;                          //  overlay: 8192x4096 bf16 (xbcdt dead after conv+dt)
    u16* convO = (u16*)(ws + 140509184ULL);     //  8192x4352 bf16 = 71,303,168
    u16* u_bf = convO;                          //  overlay: 33,554,432 (dead before conv writes)
    u16* win_bf = (u16*)(ws + 174063616ULL);    //  overlay: 35,127,296 (dead before conv writes)
    u16* wout_bf = convO;                       //  overlay: 16,777,216 (after ssm)
    float* dtp = (float*)(ws + 211812352ULL);   //  8192x64 f32 = 2,097,152
    float* CBb = (float*)(ws + 213909504ULL);   //  128x64x64 f32 = 2,097,152

    tobf16_kernel<<<16384, 256, 0, stream>>>(u, u_bf, 4194304);
    winpad_kernel<<<17152, 256, 0, stream>>>(W_in, win_bf);
    gemm_bt<1><<<dim3(32, 64), 256, 0, stream>>>(u_bf, win_bf, z_bf, 2048, 4096);
    gemm_bt<1><<<dim3(35, 64), 256, 0, stream>>>(u_bf, win_bf + (size_t)4096 * 2048, xbcdt, 2048, XBC_LD);
    conv_kernel<<<dim3(17, 8192), 256, 0, stream>>>(xbcdt, conv_w, conv_b, convO);
    dt_kernel<<<2048, 256, 0, stream>>>(xbcdt, dt_bias, dtp);
    cb_kernel<<<128, 256, 0, stream>>>(convO, CBb);
    ssm_mfma<<<512, 256, 0, stream>>>(convO, dtp, CBb, A_log, Dv, y_bf);
    tobf16_kernel<<<8192, 256, 0, stream>>>(W_out, wout_bf, 2097152);
    gate_norm<<<8192, 256, 0, stream>>>(z_bf, normw, y_bf);
    gemm_bt<0><<<dim3(16, 64), 256, 0, stream>>>(y_bf, wout_bf, out, 4096, 2048);
}

// Round 4
// 1033.891 us; speedup vs baseline: 1.0959x; 1.0959x over previous
//
#include <hip/hip_runtime.h>

typedef unsigned short u16;
typedef __attribute__((ext_vector_type(4))) float f4;
typedef __attribute__((ext_vector_type(8))) __bf16 bf16x8;
typedef __attribute__((ext_vector_type(4))) float f32x4;

#define D_MODEL 2048
#define D_SSM 4096
#define D_STATE 128
#define NHEADS 64
#define HEADDIM 64
#define CHUNK 64
#define LTOT 4096
#define NB 2
#define CONV_DIM 4352
#define XBC_LD 4480   // 4352 conv channels + 64 dt + 64 pad
#define LOG2E 1.4426950408889634f

__device__ inline float bf2f(unsigned v) { return __uint_as_float(v << 16); }
__device__ inline u16 f2bf(float f) {
    unsigned u = __float_as_uint(f);
    unsigned r = (u + 0x7fffu + ((u >> 16) & 1u)) >> 16;
    return (u16)r;
}
__device__ inline unsigned pack2(float a, float b) {
    return (unsigned)f2bf(a) | ((unsigned)f2bf(b) << 16);
}
// raw v_exp_f32: input in log2 domain
__device__ inline float fexp2(float x) {
    float r;
    asm("v_exp_f32 %0, %1" : "=v"(r) : "v"(x));
    return r;
}
// packed f32x2 -> bf16x2 (RNE), one instruction
__device__ inline unsigned cvtpk(float lo, float hi) {
    unsigned r;
    asm("v_cvt_pk_bf16_f32 %0, %1, %2" : "=v"(r) : "v"(lo), "v"(hi));
    return r;
}
__device__ inline void gload_lds16(const void* g, void* l) {
    __builtin_amdgcn_global_load_lds((const __attribute__((address_space(1))) void*)g,
                                     (__attribute__((address_space(3))) void*)l, 16, 0, 0);
}

// ---------------- f32 -> bf16 cast ----------------
__global__ __launch_bounds__(256) void tobf16_kernel(const float* __restrict__ src,
                                                     u16* __restrict__ dst, int n4) {
    int i = blockIdx.x * 256 + threadIdx.x;
    if (i < n4) {
        f4 v = ((const f4*)src)[i];
        uint2 pk;
        pk.x = pack2(v[0], v[1]);
        pk.y = pack2(v[2], v[3]);
        ((uint2*)dst)[i] = pk;
    }
}

// W_in (8512 x 2048) f32 -> win_bf (8704 x 2048) bf16, pad rows zero
// (4096 z rows + 4608 xbc/dt rows so the N=4480 GEMM can run with 256-wide tiles)
__global__ __launch_bounds__(256) void winpad_kernel(const float* __restrict__ src,
                                                     u16* __restrict__ dst) {
    int i = blockIdx.x * 256 + threadIdx.x;
    if (i >= (8704 * 2048 / 4)) return;
    int col4 = i & 511;
    int row = i >> 9;
    f4 v = {0.f, 0.f, 0.f, 0.f};
    if (row < 8512) v = ((const f4*)src)[row * 512 + col4];
    uint2 pk;
    pk.x = pack2(v[0], v[1]);
    pk.y = pack2(v[2], v[3]);
    ((uint2*)dst)[i] = pk;
}

// ---------------- GEMM 256x256: C[m,n] = sum_k A[m,k]*B[n,k]; bf16 in ----------------
// 512 threads = 8 waves (2M x 4N), per-wave output 128x64, BK=64, 128KB LDS dbuf.
// T2: LDS stored with 16B-block XOR swizzle (block ^= row&7), realized by
// pre-swizzling the GLOBAL source per lane (linear LDS dest for global_load_lds)
// and XOR-adjusting the ds_read address. T3/T4: stage one full K-tile ahead,
// counted s_waitcnt vmcnt(8) (never 0 in main loop). T5: setprio around MFMA.
// T1: bijective XCD swizzle of the linear workgroup id (all grids %8==0).
template <int OUT_BF16>
__global__ __launch_bounds__(512, 2) void gemm256(const u16* __restrict__ A,
                                                  const u16* __restrict__ Bm,
                                                  void* __restrict__ Cp,
                                                  int K, int ldC, int Nreal) {
    __shared__ __align__(16) u16 lds[2][32768];  // [buf][A 16384 | B 16384] elems

    int t = threadIdx.x;
    int w = t >> 6, lane = t & 63;
    int fm = lane & 15, fq = lane >> 4;
    int wm = w >> 2, wn = w & 3;

    // XCD swizzle (contiguous ids per XCD -> shared A/B panels in one L2)
    int gx = gridDim.x;
    int nwg = gx * gridDim.y;
    int orig = blockIdx.y * gx + blockIdx.x;
    int wg = (orig & 7) * (nwg >> 3) + (orig >> 3);
    int blockN = (wg % gx) * 256;
    int blockM = (wg / gx) * 256;

    // staging map: thread t loads 16B; LDS dest linear; global source pre-swizzled
    int srow = t >> 3;                                       // row within a 64-row block
    int scol = ((((t & 7) << 4) ^ ((srow & 7) << 4)) >> 1);  // swizzled col (elems)
    const u16* Asrc = A + (size_t)(blockM + srow) * K + scol;
    const u16* Bsrc = Bm + (size_t)(blockN + srow) * K + scol;

    f32x4 acc[8][4] = {};

    int kso0 = (((fq * 16) ^ ((fm & 7) << 4)) >> 1);        // swizzled k-offset, ks=0
    int kso1 = (((64 + fq * 16) ^ ((fm & 7) << 4)) >> 1);   // ks=1

    int nt = K >> 6;
    // prologue: stage tile 0 -> buf 0
#pragma unroll
    for (int h = 0; h < 2; ++h)
#pragma unroll
        for (int s = 0; s < 2; ++s) {
            gload_lds16(Asrc + (size_t)(h * 128 + s * 64) * K,
                        &lds[0][(h * 128 + s * 64) * 64 + t * 8]);
            gload_lds16(Bsrc + (size_t)(h * 128 + s * 64) * K,
                        &lds[0][16384 + (h * 128 + s * 64) * 64 + t * 8]);
        }

    int d = 0;
    for (int kt = 0; kt < nt; ++kt, d ^= 1) {
        if (kt + 1 < nt) {
            int e = d ^ 1;
            const u16* a1 = Asrc + (kt + 1) * 64;
            const u16* b1 = Bsrc + (kt + 1) * 64;
#pragma unroll
            for (int h = 0; h < 2; ++h)
#pragma unroll
                for (int s = 0; s < 2; ++s) {
                    gload_lds16(a1 + (size_t)(h * 128 + s * 64) * K,
                                &lds[e][(h * 128 + s * 64) * 64 + t * 8]);
                    gload_lds16(b1 + (size_t)(h * 128 + s * 64) * K,
                                &lds[e][16384 + (h * 128 + s * 64) * 64 + t * 8]);
                }
            asm volatile("s_waitcnt vmcnt(8)" ::: "memory");  // tile kt landed; kt+1 in flight
        } else {
            asm volatile("s_waitcnt vmcnt(0)" ::: "memory");
        }
        __syncthreads();

        const u16* aP = &lds[d][(wm * 128 + fm) * 64];
        const u16* bP = &lds[d][16384 + (wn * 64 + fm) * 64];
#pragma unroll
        for (int ks = 0; ks < 2; ++ks) {
            int kso = ks ? kso1 : kso0;
            bf16x8 bfv[4];
#pragma unroll
            for (int nf = 0; nf < 4; ++nf) bfv[nf] = *(const bf16x8*)(bP + nf * 1024 + kso);
#pragma unroll
            for (int mh = 0; mh < 2; ++mh) {
                bf16x8 af[4];
#pragma unroll
                for (int i = 0; i < 4; ++i)
                    af[i] = *(const bf16x8*)(aP + (mh * 4 + i) * 1024 + kso);
                __builtin_amdgcn_s_setprio(1);
#pragma unroll
                for (int i = 0; i < 4; ++i)
#pragma unroll
                    for (int nf = 0; nf < 4; ++nf)
                        acc[mh * 4 + i][nf] = __builtin_amdgcn_mfma_f32_16x16x32_bf16(
                            af[i], bfv[nf], acc[mh * 4 + i][nf], 0, 0, 0);
                __builtin_amdgcn_s_setprio(0);
            }
        }
        __syncthreads();
    }

    // epilogue
    int rb = blockM + wm * 128 + fq * 4;
    int cb = blockN + wn * 64 + fm;
    if (OUT_BF16) {
        u16* C = (u16*)Cp;
#pragma unroll
        for (int i = 0; i < 8; ++i)
#pragma unroll
            for (int nf = 0; nf < 4; ++nf) {
                int col = cb + nf * 16;
                if (col < Nreal) {
#pragma unroll
                    for (int r = 0; r < 4; ++r)
                        C[(size_t)(rb + i * 16 + r) * ldC + col] = f2bf(acc[i][nf][r]);
                }
            }
    } else {
        float* C = (float*)Cp;
#pragma unroll
        for (int i = 0; i < 8; ++i)
#pragma unroll
            for (int nf = 0; nf < 4; ++nf) {
                int col = cb + nf * 16;
                if (col < Nreal) {
#pragma unroll
                    for (int r = 0; r < 4; ++r)
                        C[(size_t)(rb + i * 16 + r) * ldC + col] = acc[i][nf][r];
                }
            }
    }
}

// ---------------- depthwise causal conv(4) + bias + silu; bf16 in/out ----------------
__global__ __launch_bounds__(256) void conv_kernel(const u16* __restrict__ xbcdt,
                                                   const float* __restrict__ conv_w,
                                                   const float* __restrict__ conv_b,
                                                   u16* __restrict__ convO) {
    int ch = blockIdx.x * 256 + threadIdx.x;  // 17*256 = 4352 exact
    int row = blockIdx.y;                     // 8192
    int l = row & (LTOT - 1);
    f4 w = *(const f4*)&conv_w[ch * 4];
    float acc = conv_b[ch];
#pragma unroll
    for (int k = 0; k < 4; ++k) {
        int ls = l - 3 + k;
        if (ls >= 0) acc += bf2f(xbcdt[(size_t)(row - 3 + k) * XBC_LD + ch]) * w[k];
    }
    convO[(size_t)row * CONV_DIM + ch] = f2bf(acc / (1.f + __expf(-acc)));
}

// ---------------- dt = softplus(raw + bias) -> dtp[row][h] f32 ----------------
__global__ __launch_bounds__(256) void dt_kernel(const u16* __restrict__ xbcdt,
                                                 const float* __restrict__ dt_bias,
                                                 float* __restrict__ dtp) {
    int idx = blockIdx.x * 256 + threadIdx.x;
    if (idx >= NB * LTOT * NHEADS) return;
    int row = idx >> 6, h = idx & 63;
    float x = bf2f(xbcdt[(size_t)row * XBC_LD + CONV_DIM + h]) + dt_bias[h];
    dtp[idx] = (x > 15.f) ? x : log1pf(__expf(x));
}

// ---------------- CB[l,s] = sum_n C[l,n]*B[s,n] per (b,c) -> CBb f32 ----------------
__global__ __launch_bounds__(256) void cb_kernel(const u16* __restrict__ convO,
                                                 float* __restrict__ CBb) {
    __shared__ u16 Bt[128 * 68];  // [n][s]
    __shared__ u16 Ct[128 * 68];  // [n][l]
    int bc = blockIdx.x;
    int c = bc & 63, b = bc >> 6;
    int rowbase = b * LTOT + c * CHUNK;
    int t = threadIdx.x;
#pragma unroll
    for (int i = 0; i < 32; i++) {
        int idx = i * 256 + t;
        int s = idx >> 7, n = idx & 127;
        Bt[n * 68 + s] = convO[(size_t)(rowbase + s) * CONV_DIM + D_SSM + n];
        Ct[n * 68 + s] = convO[(size_t)(rowbase + s) * CONV_DIM + D_SSM + D_STATE + n];
    }
    __syncthreads();
    int sq = t & 15, lq = t >> 4;
    f4 acc[4] = {};
#pragma unroll 4
    for (int n = 0; n < 128; n++) {
        ushort4 bv = *(const ushort4*)&Bt[n * 68 + sq * 4];
        ushort4 cv = *(const ushort4*)&Ct[n * 68 + lq * 4];
        f4 bf;
        bf[0] = bf2f(bv.x); bf[1] = bf2f(bv.y); bf[2] = bf2f(bv.z); bf[3] = bf2f(bv.w);
        float c0 = bf2f(cv.x), c1 = bf2f(cv.y), c2 = bf2f(cv.z), c3 = bf2f(cv.w);
        acc[0] += c0 * bf; acc[1] += c1 * bf; acc[2] += c2 * bf; acc[3] += c3 * bf;
    }
    float* outb = CBb + (size_t)bc * 4096;
#pragma unroll
    for (int j = 0; j < 4; j++) *(f4*)&outb[(lq * 4 + j) * 64 + sq * 4] = acc[j];
}

// ---------------- fused SSM (deep-prefetch pipeline, low-issue-count version) -------
__global__ __launch_bounds__(256, 2) void ssm_mfma(const u16* __restrict__ convO,
                                                   const float* __restrict__ dtp,
                                                   const float* __restrict__ CBb,
                                                   const float* __restrict__ A_log,
                                                   const float* __restrict__ Dvec,
                                                   u16* __restrict__ ybf) {
    __shared__ __align__(16) u16 xT[2][16 * 72];    // [p'][l]
    __shared__ __align__(16) u16 BT[2][128 * 64];   // [n][l swizzled 16B blocks]
    __shared__ __align__(16) u16 Sd[2][16 * 136];   // [p'][n]
    __shared__ __align__(16) float scal[2][256];    // dts | acs(log2) | wls | els

    int t = threadIdx.x;
    int w = t >> 6, lane = t & 63;
    int z = blockIdx.x;
    int pg = z & 3, h = (z >> 2) & 63, b = z >> 8;
    int pbase = h * 64 + pg * 16;
    float Ah2 = -__expf(A_log[h]) * LOG2E;  // log2-domain decay rate
    float Dh = Dvec[h];

    int fm = lane & 15;        // within-tile row/col index
    int fq = lane >> 4;        // quad 0..3
    int fk = fq * 8;           // k-base within a 32-wide k-step
    int sl = t & 63;           // xT staging: row l
    int sq = t >> 6;           // xT staging: quarter
    int lq = t & 15;           // BT staging: l-quad (rows 4lq..4lq+3)
    int no = t >> 4;           // BT staging: n-octet (cols no*8..no*8+7)

    f32x4 sacc[2] = {};        // state acc: element (p' = fq*4+r, n = 32w+16nt+fm)

    const float* CBbase = CBb + (size_t)(b * 64) * 4096;
    int yl = 16 * w + fm;      // A-operand row l for Y mfmas
    int btc0 = (32 * w + fm) * 64;          // BT col base, nt=0
    int fm7 = fm & 7;

    // ---------- prologue: stage chunk 0 into buffers[0]; load operands for chunk 0 ----
    bf16x8 afr[4];             // C rows for current chunk (loaded one iter ahead)
    f4 cbr[2][2];              // CB rows for current chunk
    {
        int rowbase = b * LTOT;
        const u16* rowp = convO + (size_t)rowbase * CONV_DIM;
        const u16* Cg = rowp + (size_t)yl * CONV_DIM + D_SSM + D_STATE;
#pragma unroll
        for (int kk = 0; kk < 4; ++kk) afr[kk] = *(const bf16x8*)(Cg + kk * 32 + fk);
        const float* CBrow = CBbase + yl * 64;
#pragma unroll
        for (int kk = 0; kk < 2; ++kk) {
            cbr[kk][0] = *(const f4*)&CBrow[kk * 32 + fk];
            cbr[kk][1] = *(const f4*)&CBrow[kk * 32 + fk + 4];
        }
        if (t < 64) {
            float dtv = dtp[(size_t)(rowbase + t) * 64 + h];
            float v = dtv * Ah2;
#pragma unroll
            for (int off = 1; off < 64; off <<= 1) {
                float pv = __shfl_up(v, off, 64);
                if (t >= off) v += pv;
            }
            float alast = __shfl(v, 63, 64);
            scal[0][t] = dtv;
            scal[0][64 + t] = v;
            scal[0][128 + t] = dtv * fexp2(alast - v);
            scal[0][192 + t] = fexp2(v);
        }
        ushort4 xv = *(const ushort4*)(rowp + (size_t)sl * CONV_DIM + pbase + sq * 4);
        xT[0][(sq * 4 + 0) * 72 + sl] = xv.x;
        xT[0][(sq * 4 + 1) * 72 + sl] = xv.y;
        xT[0][(sq * 4 + 2) * 72 + sl] = xv.z;
        xT[0][(sq * 4 + 3) * 72 + sl] = xv.w;
        {   // BT[0] staging
            const u16* bp = rowp + D_SSM + no * 8;
            union { uint4 v; unsigned ww[4]; } q[4];
#pragma unroll
            for (int r = 0; r < 4; ++r) q[r].v = *(const uint4*)(bp + (size_t)(4 * lq + r) * CONV_DIM);
            int base = no * 512 + (lq & 1) * 4;
            int lqh = lq >> 1;
#pragma unroll
            for (int j = 0; j < 8; ++j) {
                unsigned sel = (j & 1) ? 0x07060302u : 0x05040100u;
                uint2 pk;
                pk.x = __builtin_amdgcn_perm(q[1].ww[j >> 1], q[0].ww[j >> 1], sel);
                pk.y = __builtin_amdgcn_perm(q[3].ww[j >> 1], q[2].ww[j >> 1], sel);
                *(uint2*)&BT[0][base + j * 64 + ((lqh ^ j) << 3)] = pk;
            }
        }
#pragma unroll
        for (int nt = 0; nt < 2; ++nt)
#pragma unroll
            for (int r = 0; r < 4; ++r)
                Sd[0][(fq * 4 + r) * 136 + 32 * w + 16 * nt + fm] = 0;
        __syncthreads();
    }

    f4 ydef = {0.f, 0.f, 0.f, 0.f};   // deferred y values for chunk c-1
    int cur = 0;
    for (int c = 0; c < 64; ++c, cur ^= 1) {
        int rowbase = b * LTOT + c * CHUNK;
        const u16* rowp = convO + (size_t)rowbase * CONV_DIM;

        // ---- deferred y store for chunk c-1 ----
        if (c > 0) {
            unsigned y01 = cvtpk(ydef[0], ydef[1]);
            unsigned y23 = cvtpk(ydef[2], ydef[3]);
            u16* yp = ybf + (size_t)(rowbase - CHUNK + 16 * w + fq * 4) * D_SSM + pbase + fm;
            yp[0] = (u16)y01;
            yp[D_SSM] = (u16)(y01 >> 16);
            yp[2 * D_SSM] = (u16)y23;
            yp[3 * D_SSM] = (u16)(y23 >> 16);
        }

        // ---- next-chunk prefetch (C, CB rows; B-tile; x-tile; dt) ----
        bf16x8 afr_n[4] = {};
        f4 cbr_n[2][2] = {};
        uint4 bv0 = {}, bv1 = {}, bv2 = {}, bv3 = {};
        ushort4 xv = {0, 0, 0, 0};
        float dtv = 0.f;
        if (c < 63) {
            const u16* rowp1 = rowp + (size_t)CHUNK * CONV_DIM;
            const u16* Cg = rowp1 + (size_t)yl * CONV_DIM + D_SSM + D_STATE;
#pragma unroll
            for (int kk = 0; kk < 4; ++kk) afr_n[kk] = *(const bf16x8*)(Cg + kk * 32 + fk);
            const float* CBrow = CBbase + (size_t)(c + 1) * 4096 + yl * 64;
#pragma unroll
            for (int kk = 0; kk < 2; ++kk) {
                cbr_n[kk][0] = *(const f4*)&CBrow[kk * 32 + fk];
                cbr_n[kk][1] = *(const f4*)&CBrow[kk * 32 + fk + 4];
            }
            const u16* bp = rowp1 + D_SSM + no * 8;
            bv0 = *(const uint4*)(bp + (size_t)(4 * lq + 0) * CONV_DIM);
            bv1 = *(const uint4*)(bp + (size_t)(4 * lq + 1) * CONV_DIM);
            bv2 = *(const uint4*)(bp + (size_t)(4 * lq + 2) * CONV_DIM);
            bv3 = *(const uint4*)(bp + (size_t)(4 * lq + 3) * CONV_DIM);
            xv = *(const ushort4*)(rowp1 + (size_t)sl * CONV_DIM + pbase + sq * 4);
            if (t < 64) dtv = dtp[(size_t)(rowbase + CHUNK + t) * 64 + h];
        }

        const float* sc = scal[cur];
        const u16* xTc = xT[cur];
        const u16* BTc = BT[cur];
        const u16* Sdc = Sd[cur];

        // ---- LDS register loads ----
        union { uint4 v; u16 us[8]; bf16x8 bv; } xx0, xx1;
        xx0.v = *(const uint4*)&xTc[fm * 72 + fk];
        xx1.v = *(const uint4*)&xTc[fm * 72 + 32 + fk];
        ushort4 xe = *(const ushort4*)&xTc[fm * 72 + 16 * w + fq * 4];
        f4 els4 = *(const f4*)&sc[192 + 16 * w + fq * 4];
        float acl = sc[64 + yl];
        float cd = sc[192 + 63];
        f4 ac00 = *(const f4*)&sc[64 + fk], ac01 = *(const f4*)&sc[64 + fk + 4];
        f4 ac10 = *(const f4*)&sc[96 + fk], ac11 = *(const f4*)&sc[96 + fk + 4];
        f4 dt00 = *(const f4*)&sc[fk], dt01 = *(const f4*)&sc[fk + 4];
        f4 dt10 = *(const f4*)&sc[32 + fk], dt11 = *(const f4*)&sc[32 + fk + 4];
        f4 w00 = *(const f4*)&sc[128 + fk], w01 = *(const f4*)&sc[128 + fk + 4];
        f4 w10 = *(const f4*)&sc[160 + fk], w11 = *(const f4*)&sc[160 + fk + 4];
        bf16x8 sdf0 = *(const bf16x8*)&Sdc[fm * 136 + fk];
        bf16x8 sdf1 = *(const bf16x8*)&Sdc[fm * 136 + 32 + fk];
        bf16x8 sdf2 = *(const bf16x8*)&Sdc[fm * 136 + 64 + fk];
        bf16x8 sdf3 = *(const bf16x8*)&Sdc[fm * 136 + 96 + fk];
        int pb0 = (fq ^ fm7) << 3;
        int pb1 = ((4 + fq) ^ fm7) << 3;
        bf16x8 btf00 = *(const bf16x8*)&BTc[btc0 + pb0];
        bf16x8 btf01 = *(const bf16x8*)&BTc[btc0 + 1024 + pb0];
        bf16x8 btf10 = *(const bf16x8*)&BTc[btc0 + pb1];
        bf16x8 btf11 = *(const bf16x8*)&BTc[btc0 + 1024 + pb1];

        // ---- Y_diag = G . x ----
        f32x4 ydia = {0.f, 0.f, 0.f, 0.f};
        {
            union { unsigned u[4]; bf16x8 v; } gu;
            float g[8];
#pragma unroll
            for (int j = 0; j < 4; ++j) {
                int s = fk + j;
                g[j] = (s <= yl) ? cbr[0][0][j] * fexp2(acl - ac00[j]) * dt00[j] : 0.f;
            }
#pragma unroll
            for (int j = 0; j < 4; ++j) {
                int s = fk + 4 + j;
                g[4 + j] = (s <= yl) ? cbr[0][1][j] * fexp2(acl - ac01[j]) * dt01[j] : 0.f;
            }
            gu.u[0] = cvtpk(g[0], g[1]);
            gu.u[1] = cvtpk(g[2], g[3]);
            gu.u[2] = cvtpk(g[4], g[5]);
            gu.u[3] = cvtpk(g[6], g[7]);
            ydia = __builtin_amdgcn_mfma_f32_16x16x32_bf16(gu.v, xx0.bv, ydia, 0, 0, 0);
#pragma unroll
            for (int j = 0; j < 4; ++j) {
                int s = 32 + fk + j;
                g[j] = (s <= yl) ? cbr[1][0][j] * fexp2(acl - ac10[j]) * dt10[j] : 0.f;
            }
#pragma unroll
            for (int j = 0; j < 4; ++j) {
                int s = 32 + fk + 4 + j;
                g[4 + j] = (s <= yl) ? cbr[1][1][j] * fexp2(acl - ac11[j]) * dt11[j] : 0.f;
            }
            gu.u[0] = cvtpk(g[0], g[1]);
            gu.u[1] = cvtpk(g[2], g[3]);
            gu.u[2] = cvtpk(g[4], g[5]);
            gu.u[3] = cvtpk(g[6], g[7]);
            ydia = __builtin_amdgcn_mfma_f32_16x16x32_bf16(gu.v, xx1.bv, ydia, 0, 0, 0);
        }

        // ---- state update: S = cd*S + (w.x)^T . B ----
        sacc[0] *= cd;
        sacc[1] *= cd;
        {
            union { unsigned u[4]; bf16x8 v; } au;
            float xf[8];
#pragma unroll
            for (int j = 0; j < 8; ++j) xf[j] = bf2f(xx0.us[j]);
            au.u[0] = cvtpk(xf[0] * w00[0], xf[1] * w00[1]);
            au.u[1] = cvtpk(xf[2] * w00[2], xf[3] * w00[3]);
            au.u[2] = cvtpk(xf[4] * w01[0], xf[5] * w01[1]);
            au.u[3] = cvtpk(xf[6] * w01[2], xf[7] * w01[3]);
            sacc[0] = __builtin_amdgcn_mfma_f32_16x16x32_bf16(au.v, btf00, sacc[0], 0, 0, 0);
            sacc[1] = __builtin_amdgcn_mfma_f32_16x16x32_bf16(au.v, btf01, sacc[1], 0, 0, 0);
#pragma unroll
            for (int j = 0; j < 8; ++j) xf[j] = bf2f(xx1.us[j]);
            au.u[0] = cvtpk(xf[0] * w10[0], xf[1] * w10[1]);
            au.u[1] = cvtpk(xf[2] * w10[2], xf[3] * w10[3]);
            au.u[2] = cvtpk(xf[4] * w11[0], xf[5] * w11[1]);
            au.u[3] = cvtpk(xf[6] * w11[2], xf[7] * w11[3]);
            sacc[0] = __builtin_amdgcn_mfma_f32_16x16x32_bf16(au.v, btf10, sacc[0], 0, 0, 0);
            sacc[1] = __builtin_amdgcn_mfma_f32_16x16x32_bf16(au.v, btf11, sacc[1], 0, 0, 0);
        }

        // ---- Y_off = C . S^T ----
        f32x4 yoff = {0.f, 0.f, 0.f, 0.f};
        yoff = __builtin_amdgcn_mfma_f32_16x16x32_bf16(afr[0], sdf0, yoff, 0, 0, 0);
        yoff = __builtin_amdgcn_mfma_f32_16x16x32_bf16(afr[1], sdf1, yoff, 0, 0, 0);
        yoff = __builtin_amdgcn_mfma_f32_16x16x32_bf16(afr[2], sdf2, yoff, 0, 0, 0);
        yoff = __builtin_amdgcn_mfma_f32_16x16x32_bf16(afr[3], sdf3, yoff, 0, 0, 0);

        // ---- combine ----
        {
            float xf0 = bf2f(xe.x), xf1 = bf2f(xe.y), xf2 = bf2f(xe.z), xf3 = bf2f(xe.w);
            ydef[0] = yoff[0] * els4[0] + ydia[0] + Dh * xf0;
            ydef[1] = yoff[1] * els4[1] + ydia[1] + Dh * xf1;
            ydef[2] = yoff[2] * els4[2] + ydia[2] + Dh * xf2;
            ydef[3] = yoff[3] * els4[3] + ydia[3] + Dh * xf3;
        }

        // ---- write phase: stage chunk c+1 into buffers[nxt] ----
        if (c < 63) {
            int nxt = cur ^ 1;
            if (t < 64) {
                float v = dtv * Ah2;
#pragma unroll
                for (int off = 1; off < 64; off <<= 1) {
                    float pv = __shfl_up(v, off, 64);
                    if (t >= off) v += pv;
                }
                float alast = __shfl(v, 63, 64);
                scal[nxt][t] = dtv;
                scal[nxt][64 + t] = v;
                scal[nxt][128 + t] = dtv * fexp2(alast - v);
                scal[nxt][192 + t] = fexp2(v);
            }
            xT[nxt][(sq * 4 + 0) * 72 + sl] = xv.x;
            xT[nxt][(sq * 4 + 1) * 72 + sl] = xv.y;
            xT[nxt][(sq * 4 + 2) * 72 + sl] = xv.z;
            xT[nxt][(sq * 4 + 3) * 72 + sl] = xv.w;
            {
                union { uint4 v; unsigned ww[4]; } q0, q1, q2, q3;
                q0.v = bv0; q1.v = bv1; q2.v = bv2; q3.v = bv3;
                int base = no * 512 + (lq & 1) * 4;
                int lqh = lq >> 1;
#pragma unroll
                for (int j = 0; j < 8; ++j) {
                    unsigned sel = (j & 1) ? 0x07060302u : 0x05040100u;
                    uint2 pk;
                    pk.x = __builtin_amdgcn_perm(q1.ww[j >> 1], q0.ww[j >> 1], sel);
                    pk.y = __builtin_amdgcn_perm(q3.ww[j >> 1], q2.ww[j >> 1], sel);
                    *(uint2*)&BT[nxt][base + j * 64 + ((lqh ^ j) << 3)] = pk;
                }
            }
#pragma unroll
            for (int nt = 0; nt < 2; ++nt) {
                unsigned p01 = cvtpk(sacc[nt][0], sacc[nt][1]);
                unsigned p23 = cvtpk(sacc[nt][2], sacc[nt][3]);
                int colb = 32 * w + 16 * nt + fm;
                Sd[nxt][(fq * 4 + 0) * 136 + colb] = (u16)p01;
                Sd[nxt][(fq * 4 + 1) * 136 + colb] = (u16)(p01 >> 16);
                Sd[nxt][(fq * 4 + 2) * 136 + colb] = (u16)p23;
                Sd[nxt][(fq * 4 + 3) * 136 + colb] = (u16)(p23 >> 16);
            }
        }
        __syncthreads();

        // rotate prefetched operands
#pragma unroll
        for (int kk = 0; kk < 4; ++kk) afr[kk] = afr_n[kk];
#pragma unroll
        for (int kk = 0; kk < 2; ++kk) {
            cbr[kk][0] = cbr_n[kk][0];
            cbr[kk][1] = cbr_n[kk][1];
        }
    }

    // final deferred y store (chunk 63)
    {
        unsigned y01 = cvtpk(ydef[0], ydef[1]);
        unsigned y23 = cvtpk(ydef[2], ydef[3]);
        u16* yp = ybf + (size_t)(b * LTOT + 63 * CHUNK + 16 * w + fq * 4) * D_SSM + pbase + fm;
        yp[0] = (u16)y01;
        yp[D_SSM] = (u16)(y01 >> 16);
        yp[2 * D_SSM] = (u16)y23;
        yp[3 * D_SSM] = (u16)(y23 >> 16);
    }
}

// ---------------- gate (silu(z)) + RMSNorm, in-place on y_bf ----------------
__global__ __launch_bounds__(256) void gate_norm(const u16* __restrict__ zbf,
                                                 const float* __restrict__ normw,
                                                 u16* __restrict__ ybf) {
    int row = blockIdx.x, t = threadIdx.x;
    const uint2* y2 = (const uint2*)(ybf + (size_t)row * D_SSM);
    const uint2* z2 = (const uint2*)(zbf + (size_t)row * D_SSM);
    f4 yg[4];
    float ss = 0.f;
#pragma unroll
    for (int i = 0; i < 4; ++i) {
        int idx = i * 256 + t;
        uint2 yv = y2[idx], zv = z2[idx];
        float ya[4] = {bf2f(yv.x & 0xffffu), bf2f(yv.x >> 16), bf2f(yv.y & 0xffffu), bf2f(yv.y >> 16)};
        float za[4] = {bf2f(zv.x & 0xffffu), bf2f(zv.x >> 16), bf2f(zv.y & 0xffffu), bf2f(zv.y >> 16)};
        f4 g;
#pragma unroll
        for (int k = 0; k < 4; ++k) {
            float sz = za[k] / (1.f + __expf(-za[k]));
            g[k] = ya[k] * sz;
            ss += g[k] * g[k];
        }
        yg[i] = g;
    }
#pragma unroll
    for (int off = 32; off; off >>= 1) ss += __shfl_down(ss, off, 64);
    __shared__ float red[4];
    if ((t & 63) == 0) red[t >> 6] = ss;
    __syncthreads();
    float tot = red[0] + red[1] + red[2] + red[3];
    float scale = rsqrtf(tot / (float)D_SSM + 1e-5f);
    const f4* nw4 = (const f4*)normw;
    uint2* out = (uint2*)(ybf + (size_t)row * D_SSM);
#pragma unroll
    for (int i = 0; i < 4; ++i) {
        int idx = i * 256 + t;
        f4 v = yg[i] * scale * nw4[idx];
        uint2 pk;
        pk.x = pack2(v[0], v[1]);
        pk.y = pack2(v[2], v[3]);
        out[idx] = pk;
    }
}

// ---------------- launch ----------------
extern "C" void kernel_launch(void* const* d_in, const int* in_sizes, int n_in,
                              void* d_out, int out_size, void* d_ws, size_t ws_size,
                              hipStream_t stream) {
    const float* u = (const float*)d_in[0];
    const float* W_in = (const float*)d_in[1];
    const float* conv_w = (const float*)d_in[2];
    const float* conv_b = (const float*)d_in[3];
    const float* dt_bias = (const float*)d_in[4];
    const float* A_log = (const float*)d_in[5];
    const float* Dv = (const float*)d_in[6];
    const float* normw = (const float*)d_in[7];
    const float* W_out = (const float*)d_in[8];
    float* out = (float*)d_out;
    char* ws = (char*)d_ws;

    // workspace layout
    u16* z_bf = (u16*)(ws + 0ULL);              //  8192x4096 bf16 = 67,108,864
    u16* xbcdt = (u16*)(ws + 67108864ULL);      //  8192x4480 bf16 = 73,400,320
    u16* y_bf = xbcdt;                          //  overlay: 8192x4096 bf16
    u16* convO = (u16*)(ws + 140509184ULL);     //  8192x4352 bf16 = 71,303,168
    u16* u_bf = convO;                          //  overlay: 33,554,432
    u16* win_bf = (u16*)(ws + 174063616ULL);    //  overlay: 8704x2048 bf16 = 35,651,584
    u16* wout_bf = convO;                       //  overlay: 16,777,216 (after ssm)
    float* dtp = (float*)(ws + 211812352ULL);   //  8192x64 f32 = 2,097,152
    float* CBb = (float*)(ws + 213909504ULL);   //  128x64x64 f32 = 2,097,152

    tobf16_kernel<<<16384, 256, 0, stream>>>(u, u_bf, 4194304);
    winpad_kernel<<<17408, 256, 0, stream>>>(W_in, win_bf);
    gemm256<1><<<dim3(16, 32), 512, 0, stream>>>(u_bf, win_bf, z_bf, 2048, 4096, 4096);
    gemm256<1><<<dim3(18, 32), 512, 0, stream>>>(u_bf, win_bf + (size_t)4096 * 2048, xbcdt, 2048, XBC_LD, 4480);
    conv_kernel<<<dim3(17, 8192), 256, 0, stream>>>(xbcdt, conv_w, conv_b, convO);
    dt_kernel<<<2048, 256, 0, stream>>>(xbcdt, dt_bias, dtp);
    cb_kernel<<<128, 256, 0, stream>>>(convO, CBb);
    ssm_mfma<<<512, 256, 0, stream>>>(convO, dtp, CBb, A_log, Dv, y_bf);
    tobf16_kernel<<<8192, 256, 0, stream>>>(W_out, wout_bf, 2097152);
    gate_norm<<<8192, 256, 0, stream>>>(z_bf, normw, y_bf);
    gemm256<0><<<dim3(8, 32), 512, 0, stream>>>(y_bf, wout_bf, out, 4096, 2048, 2048);
}

// Round 5
// 972.607 us; speedup vs baseline: 1.1649x; 1.0630x over previous
//
#include <hip/hip_runtime.h>

typedef unsigned short u16;
typedef __attribute__((ext_vector_type(4))) float f4;
typedef __attribute__((ext_vector_type(8))) __bf16 bf16x8;
typedef __attribute__((ext_vector_type(4))) float f32x4;

#define D_MODEL 2048
#define D_SSM 4096
#define D_STATE 128
#define NHEADS 64
#define HEADDIM 64
#define CHUNK 64
#define LTOT 4096
#define NB 2
#define CONV_DIM 4352
#define XBC_LD 4480   // 4352 conv channels + 64 dt + 64 pad
#define LOG2E 1.4426950408889634f

__device__ inline float bf2f(unsigned v) { return __uint_as_float(v << 16); }
__device__ inline u16 f2bf(float f) {
    unsigned u = __float_as_uint(f);
    unsigned r = (u + 0x7fffu + ((u >> 16) & 1u)) >> 16;
    return (u16)r;
}
__device__ inline unsigned pack2(float a, float b) {
    return (unsigned)f2bf(a) | ((unsigned)f2bf(b) << 16);
}
// raw v_exp_f32: input in log2 domain
__device__ inline float fexp2(float x) {
    float r;
    asm("v_exp_f32 %0, %1" : "=v"(r) : "v"(x));
    return r;
}
// packed f32x2 -> bf16x2 (RNE), one instruction
__device__ inline unsigned cvtpk(float lo, float hi) {
    unsigned r;
    asm("v_cvt_pk_bf16_f32 %0, %1, %2" : "=v"(r) : "v"(lo), "v"(hi));
    return r;
}
__device__ inline void gload_lds16(const void* g, void* l) {
    __builtin_amdgcn_global_load_lds((const __attribute__((address_space(1))) void*)g,
                                     (__attribute__((address_space(3))) void*)l, 16, 0, 0);
}
__device__ inline f32x4 mfma16(bf16x8 a, bf16x8 b, f32x4 c) {
    return __builtin_amdgcn_mfma_f32_16x16x32_bf16(a, b, c, 0, 0, 0);
}

// ---------------- f32 -> bf16 cast ----------------
__global__ __launch_bounds__(256) void tobf16_kernel(const float* __restrict__ src,
                                                     u16* __restrict__ dst, int n4) {
    int i = blockIdx.x * 256 + threadIdx.x;
    if (i < n4) {
        f4 v = ((const f4*)src)[i];
        uint2 pk;
        pk.x = pack2(v[0], v[1]);
        pk.y = pack2(v[2], v[3]);
        ((uint2*)dst)[i] = pk;
    }
}

// W_in (8512 x 2048) f32 -> win_bf (8704 x 2048) bf16, pad rows zero
__global__ __launch_bounds__(256) void winpad_kernel(const float* __restrict__ src,
                                                     u16* __restrict__ dst) {
    int i = blockIdx.x * 256 + threadIdx.x;
    if (i >= (8704 * 2048 / 4)) return;
    int col4 = i & 511;
    int row = i >> 9;
    f4 v = {0.f, 0.f, 0.f, 0.f};
    if (row < 8512) v = ((const f4*)src)[row * 512 + col4];
    uint2 pk;
    pk.x = pack2(v[0], v[1]);
    pk.y = pack2(v[2], v[3]);
    ((uint2*)dst)[i] = pk;
}

// ---------------- GEMM 256x256, 8-phase counted-vmcnt schedule --------------------
// C[m,n] = sum_k A[m,k]*B[n,k]; bf16 in. 512 thr = 8 waves (2M x 4N).
// Per-wave out 128x64 split across both A-halves / B-halves so each LDS half-tile's
// last read precedes its re-stage: phase q reads {A-half(q>=2), B-half(q&1)}; stages:
// p0: A1(t+1)->bufE, p1: B1(t+1)->bufE, p2: A0(t+2)->bufD, p3: B0(t+2)->bufD.
// Counted waits BEFORE an end-of-phase barrier (vmcnt is per-wave; barrier publishes):
// vmcnt(6) @p0-end, vmcnt(8) @p3-end; epilogue drains 4 -> 0. T2 XOR swizzle via
// pre-swizzled global source (linear LDS dest) + swizzled ds_read. T5 setprio on MFMA.
template <int OUT_BF16>
__global__ __launch_bounds__(512, 1) void gemm256(const u16* __restrict__ A,
                                                  const u16* __restrict__ Bm,
                                                  void* __restrict__ Cp,
                                                  int K, int ldC, int Nreal) {
    __shared__ __align__(16) u16 lds[2][32768];  // per buf: A[0,16384) | B[16384,32768)

    int t = threadIdx.x;
    int w = t >> 6, lane = t & 63;
    int fm = lane & 15, fq = lane >> 4;
    int wm = w >> 2, wn = w & 3;

    // T1: bijective XCD swizzle (all grids have nwg % 8 == 0)
    int gx = gridDim.x;
    int nwg = gx * gridDim.y;
    int orig = blockIdx.y * gx + blockIdx.x;
    int wg = (orig & 7) * (nwg >> 3) + (orig >> 3);
    int blockN = (wg % gx) * 256;
    int blockM = (wg / gx) * 256;

    // staging map: thread t loads 16B; LDS dest linear; global source pre-swizzled.
    // row_local = t>>3 (+64 per round, +128 per half: &7 invariant), col block = (t&7)^(row&7)
    int srow = t >> 3;
    int scol = (((t & 7) ^ (srow & 7)) << 3);
    const u16* Asrc = A + (size_t)(blockM + srow) * K + scol;
    const u16* Bsrc = Bm + (size_t)(blockN + srow) * K + scol;

#define STAGE(buf, isB, half, tile)                                              \
    do {                                                                         \
        const u16* _s = ((isB) ? Bsrc : Asrc) + (size_t)(tile) * 64 +            \
                        (size_t)((half) * 128) * K;                              \
        u16* _d = &lds[buf][(isB) * 16384 + (half) * 8192 + t * 8];              \
        gload_lds16(_s, _d);                                                     \
        gload_lds16(_s + (size_t)64 * K, _d + 4096);                             \
    } while (0)

    int nt = K >> 6;
    // prologue issue order: A0(0),B0(0),A1(0),B1(0),A0(1),B0(1)
    STAGE(0, 0, 0, 0); STAGE(0, 1, 0, 0);
    STAGE(0, 0, 1, 0); STAGE(0, 1, 1, 0);
    STAGE(1, 0, 0, 1); STAGE(1, 1, 0, 1);

    f32x4 acc[8][4] = {};
    int lro = fm * 64;
    int ko0 = ((fq ^ (fm & 7)) << 3);        // swizzled 16B-block, kstep 0
    int ko1 = (((4 + fq) ^ (fm & 7)) << 3);  // kstep 1

    // gate tile 0's first halves (A0,B0 landed) and publish across waves
    asm volatile("s_waitcnt vmcnt(8)" ::: "memory");
    __builtin_amdgcn_s_barrier();

    for (int kt = 0; kt < nt; ++kt) {
        int d = kt & 1, e = d ^ 1;
        const u16* aH0 = &lds[d][wm * 4096 + lro];
        const u16* aH1 = aH0 + 8192;
        const u16* bH0 = &lds[d][16384 + wn * 2048 + lro];
        const u16* bH1 = bH0 + 8192;
        bf16x8 af[4][2], bfr[2][2];

        // ---------------- phase 0: M0-3 x N0-1 ----------------
#pragma unroll
        for (int i = 0; i < 4; ++i) {
            af[i][0] = *(const bf16x8*)(aH0 + i * 1024 + ko0);
            af[i][1] = *(const bf16x8*)(aH0 + i * 1024 + ko1);
        }
#pragma unroll
        for (int j = 0; j < 2; ++j) {
            bfr[j][0] = *(const bf16x8*)(bH0 + j * 1024 + ko0);
            bfr[j][1] = *(const bf16x8*)(bH0 + j * 1024 + ko1);
        }
        if (kt + 1 < nt) STAGE(e, 0, 1, kt + 1);
        __builtin_amdgcn_s_barrier();
        __builtin_amdgcn_s_setprio(1);
#pragma unroll
        for (int i = 0; i < 4; ++i)
#pragma unroll
            for (int j = 0; j < 2; ++j) {
                acc[i][j] = mfma16(af[i][0], bfr[j][0], acc[i][j]);
                acc[i][j] = mfma16(af[i][1], bfr[j][1], acc[i][j]);
            }
        __builtin_amdgcn_s_setprio(0);
        if (kt == nt - 1) asm volatile("s_waitcnt vmcnt(0)" ::: "memory");
        else              asm volatile("s_waitcnt vmcnt(6)" ::: "memory");
        __builtin_amdgcn_s_barrier();

        // ---------------- phase 1: M0-3 x N2-3 ----------------
#pragma unroll
        for (int j = 0; j < 2; ++j) {
            bfr[j][0] = *(const bf16x8*)(bH1 + j * 1024 + ko0);
            bfr[j][1] = *(const bf16x8*)(bH1 + j * 1024 + ko1);
        }
        if (kt + 1 < nt) STAGE(e, 1, 1, kt + 1);
        __builtin_amdgcn_s_barrier();
        __builtin_amdgcn_s_setprio(1);
#pragma unroll
        for (int i = 0; i < 4; ++i)
#pragma unroll
            for (int j = 0; j < 2; ++j) {
                acc[i][2 + j] = mfma16(af[i][0], bfr[j][0], acc[i][2 + j]);
                acc[i][2 + j] = mfma16(af[i][1], bfr[j][1], acc[i][2 + j]);
            }
        __builtin_amdgcn_s_setprio(0);
        __builtin_amdgcn_s_barrier();

        // ---------------- phase 2: M4-7 x N0-1 ----------------
#pragma unroll
        for (int i = 0; i < 4; ++i) {
            af[i][0] = *(const bf16x8*)(aH1 + i * 1024 + ko0);
            af[i][1] = *(const bf16x8*)(aH1 + i * 1024 + ko1);
        }
#pragma unroll
        for (int j = 0; j < 2; ++j) {
            bfr[j][0] = *(const bf16x8*)(bH0 + j * 1024 + ko0);
            bfr[j][1] = *(const bf16x8*)(bH0 + j * 1024 + ko1);
        }
        if (kt + 2 < nt) STAGE(d, 0, 0, kt + 2);
        __builtin_amdgcn_s_barrier();
        __builtin_amdgcn_s_setprio(1);
#pragma unroll
        for (int i = 0; i < 4; ++i)
#pragma unroll
            for (int j = 0; j < 2; ++j) {
                acc[4 + i][j] = mfma16(af[i][0], bfr[j][0], acc[4 + i][j]);
                acc[4 + i][j] = mfma16(af[i][1], bfr[j][1], acc[4 + i][j]);
            }
        __builtin_amdgcn_s_setprio(0);
        __builtin_amdgcn_s_barrier();

        // ---------------- phase 3: M4-7 x N2-3 ----------------
#pragma unroll
        for (int j = 0; j < 2; ++j) {
            bfr[j][0] = *(const bf16x8*)(bH1 + j * 1024 + ko0);
            bfr[j][1] = *(const bf16x8*)(bH1 + j * 1024 + ko1);
        }
        if (kt + 2 < nt) STAGE(d, 1, 0, kt + 2);
        __builtin_amdgcn_s_barrier();
        __builtin_amdgcn_s_setprio(1);
#pragma unroll
        for (int i = 0; i < 4; ++i)
#pragma unroll
            for (int j = 0; j < 2; ++j) {
                acc[4 + i][2 + j] = mfma16(af[i][0], bfr[j][0], acc[4 + i][2 + j]);
                acc[4 + i][2 + j] = mfma16(af[i][1], bfr[j][1], acc[4 + i][2 + j]);
            }
        __builtin_amdgcn_s_setprio(0);
        if (kt == nt - 2)      asm volatile("s_waitcnt vmcnt(4)" ::: "memory");
        else if (kt < nt - 2)  asm volatile("s_waitcnt vmcnt(8)" ::: "memory");
        __builtin_amdgcn_s_barrier();
    }
#undef STAGE

    // epilogue
#pragma unroll
    for (int i = 0; i < 8; ++i) {
        int rbase = (i < 4) ? (wm * 64 + i * 16) : (128 + wm * 64 + (i - 4) * 16);
        int row = blockM + rbase + fq * 4;
#pragma unroll
        for (int j = 0; j < 4; ++j) {
            int cbase = (j < 2) ? (wn * 32 + j * 16) : (128 + wn * 32 + (j - 2) * 16);
            int col = blockN + cbase + fm;
            if (col < Nreal) {
                if (OUT_BF16) {
                    u16* C = (u16*)Cp;
#pragma unroll
                    for (int r = 0; r < 4; ++r)
                        C[(size_t)(row + r) * ldC + col] = f2bf(acc[i][j][r]);
                } else {
                    float* C = (float*)Cp;
#pragma unroll
                    for (int r = 0; r < 4; ++r)
                        C[(size_t)(row + r) * ldC + col] = acc[i][j][r];
                }
            }
        }
    }
}

// ---------------- depthwise causal conv(4) + bias + silu; bf16 in/out ----------------
__global__ __launch_bounds__(256) void conv_kernel(const u16* __restrict__ xbcdt,
                                                   const float* __restrict__ conv_w,
                                                   const float* __restrict__ conv_b,
                                                   u16* __restrict__ convO) {
    int ch = blockIdx.x * 256 + threadIdx.x;  // 17*256 = 4352 exact
    int row = blockIdx.y;                     // 8192
    int l = row & (LTOT - 1);
    f4 w = *(const f4*)&conv_w[ch * 4];
    float acc = conv_b[ch];
#pragma unroll
    for (int k = 0; k < 4; ++k) {
        int ls = l - 3 + k;
        if (ls >= 0) acc += bf2f(xbcdt[(size_t)(row - 3 + k) * XBC_LD + ch]) * w[k];
    }
    convO[(size_t)row * CONV_DIM + ch] = f2bf(acc / (1.f + __expf(-acc)));
}

// ---------------- dt = softplus(raw + bias) -> dtp[row][h] f32 ----------------
__global__ __launch_bounds__(256) void dt_kernel(const u16* __restrict__ xbcdt,
                                                 const float* __restrict__ dt_bias,
                                                 float* __restrict__ dtp) {
    int idx = blockIdx.x * 256 + threadIdx.x;
    if (idx >= NB * LTOT * NHEADS) return;
    int row = idx >> 6, h = idx & 63;
    float x = bf2f(xbcdt[(size_t)row * XBC_LD + CONV_DIM + h]) + dt_bias[h];
    dtp[idx] = (x > 15.f) ? x : log1pf(__expf(x));
}

// ---------------- CB[l,s] = sum_n C[l,n]*B[s,n] per (b,c) -> CBb f32 ----------------
__global__ __launch_bounds__(256) void cb_kernel(const u16* __restrict__ convO,
                                                 float* __restrict__ CBb) {
    __shared__ u16 Bt[128 * 68];  // [n][s]
    __shared__ u16 Ct[128 * 68];  // [n][l]
    int bc = blockIdx.x;
    int c = bc & 63, b = bc >> 6;
    int rowbase = b * LTOT + c * CHUNK;
    int t = threadIdx.x;
#pragma unroll
    for (int i = 0; i < 32; i++) {
        int idx = i * 256 + t;
        int s = idx >> 7, n = idx & 127;
        Bt[n * 68 + s] = convO[(size_t)(rowbase + s) * CONV_DIM + D_SSM + n];
        Ct[n * 68 + s] = convO[(size_t)(rowbase + s) * CONV_DIM + D_SSM + D_STATE + n];
    }
    __syncthreads();
    int sq = t & 15, lq = t >> 4;
    f4 acc[4] = {};
#pragma unroll 4
    for (int n = 0; n < 128; n++) {
        ushort4 bv = *(const ushort4*)&Bt[n * 68 + sq * 4];
        ushort4 cv = *(const ushort4*)&Ct[n * 68 + lq * 4];
        f4 bf;
        bf[0] = bf2f(bv.x); bf[1] = bf2f(bv.y); bf[2] = bf2f(bv.z); bf[3] = bf2f(bv.w);
        float c0 = bf2f(cv.x), c1 = bf2f(cv.y), c2 = bf2f(cv.z), c3 = bf2f(cv.w);
        acc[0] += c0 * bf; acc[1] += c1 * bf; acc[2] += c2 * bf; acc[3] += c3 * bf;
    }
    float* outb = CBb + (size_t)bc * 4096;
#pragma unroll
    for (int j = 0; j < 4; j++) *(f4*)&outb[(lq * 4 + j) * 64 + sq * 4] = acc[j];
}

// ---------------- fused SSM (deep-prefetch pipeline, low-issue-count version) -------
__global__ __launch_bounds__(256, 2) void ssm_mfma(const u16* __restrict__ convO,
                                                   const float* __restrict__ dtp,
                                                   const float* __restrict__ CBb,
                                                   const float* __restrict__ A_log,
                                                   const float* __restrict__ Dvec,
                                                   u16* __restrict__ ybf) {
    __shared__ __align__(16) u16 xT[2][16 * 72];    // [p'][l]
    __shared__ __align__(16) u16 BT[2][128 * 64];   // [n][l swizzled 16B blocks]
    __shared__ __align__(16) u16 Sd[2][16 * 136];   // [p'][n]
    __shared__ __align__(16) float scal[2][256];    // dts | acs(log2) | wls | els

    int t = threadIdx.x;
    int w = t >> 6, lane = t & 63;
    int z = blockIdx.x;
    int pg = z & 3, h = (z >> 2) & 63, b = z >> 8;
    int pbase = h * 64 + pg * 16;
    float Ah2 = -__expf(A_log[h]) * LOG2E;  // log2-domain decay rate
    float Dh = Dvec[h];

    int fm = lane & 15;        // within-tile row/col index
    int fq = lane >> 4;        // quad 0..3
    int fk = fq * 8;           // k-base within a 32-wide k-step
    int sl = t & 63;           // xT staging: row l
    int sq = t >> 6;           // xT staging: quarter
    int lq = t & 15;           // BT staging: l-quad (rows 4lq..4lq+3)
    int no = t >> 4;           // BT staging: n-octet (cols no*8..no*8+7)

    f32x4 sacc[2] = {};        // state acc: element (p' = fq*4+r, n = 32w+16nt+fm)

    const float* CBbase = CBb + (size_t)(b * 64) * 4096;
    int yl = 16 * w + fm;      // A-operand row l for Y mfmas
    int btc0 = (32 * w + fm) * 64;          // BT col base, nt=0
    int fm7 = fm & 7;

    // ---------- prologue: stage chunk 0 into buffers[0]; load operands for chunk 0 ----
    bf16x8 afr[4];             // C rows for current chunk (loaded one iter ahead)
    f4 cbr[2][2];              // CB rows for current chunk
    {
        int rowbase = b * LTOT;
        const u16* rowp = convO + (size_t)rowbase * CONV_DIM;
        const u16* Cg = rowp + (size_t)yl * CONV_DIM + D_SSM + D_STATE;
#pragma unroll
        for (int kk = 0; kk < 4; ++kk) afr[kk] = *(const bf16x8*)(Cg + kk * 32 + fk);
        const float* CBrow = CBbase + yl * 64;
#pragma unroll
        for (int kk = 0; kk < 2; ++kk) {
            cbr[kk][0] = *(const f4*)&CBrow[kk * 32 + fk];
            cbr[kk][1] = *(const f4*)&CBrow[kk * 32 + fk + 4];
        }
        if (t < 64) {
            float dtv = dtp[(size_t)(rowbase + t) * 64 + h];
            float v = dtv * Ah2;
#pragma unroll
            for (int off = 1; off < 64; off <<= 1) {
                float pv = __shfl_up(v, off, 64);
                if (t >= off) v += pv;
            }
            float alast = __shfl(v, 63, 64);
            scal[0][t] = dtv;
            scal[0][64 + t] = v;
            scal[0][128 + t] = dtv * fexp2(alast - v);
            scal[0][192 + t] = fexp2(v);
        }
        ushort4 xv = *(const ushort4*)(rowp + (size_t)sl * CONV_DIM + pbase + sq * 4);
        xT[0][(sq * 4 + 0) * 72 + sl] = xv.x;
        xT[0][(sq * 4 + 1) * 72 + sl] = xv.y;
        xT[0][(sq * 4 + 2) * 72 + sl] = xv.z;
        xT[0][(sq * 4 + 3) * 72 + sl] = xv.w;
        {   // BT[0] staging
            const u16* bp = rowp + D_SSM + no * 8;
            union { uint4 v; unsigned ww[4]; } q[4];
#pragma unroll
            for (int r = 0; r < 4; ++r) q[r].v = *(const uint4*)(bp + (size_t)(4 * lq + r) * CONV_DIM);
            int base = no * 512 + (lq & 1) * 4;
            int lqh = lq >> 1;
#pragma unroll
            for (int j = 0; j < 8; ++j) {
                unsigned sel = (j & 1) ? 0x07060302u : 0x05040100u;
                uint2 pk;
                pk.x = __builtin_amdgcn_perm(q[1].ww[j >> 1], q[0].ww[j >> 1], sel);
                pk.y = __builtin_amdgcn_perm(q[3].ww[j >> 1], q[2].ww[j >> 1], sel);
                *(uint2*)&BT[0][base + j * 64 + ((lqh ^ j) << 3)] = pk;
            }
        }
#pragma unroll
        for (int nt = 0; nt < 2; ++nt)
#pragma unroll
            for (int r = 0; r < 4; ++r)
                Sd[0][(fq * 4 + r) * 136 + 32 * w + 16 * nt + fm] = 0;
        __syncthreads();
    }

    f4 ydef = {0.f, 0.f, 0.f, 0.f};   // deferred y values for chunk c-1
    int cur = 0;
    for (int c = 0; c < 64; ++c, cur ^= 1) {
        int rowbase = b * LTOT + c * CHUNK;
        const u16* rowp = convO + (size_t)rowbase * CONV_DIM;

        // ---- deferred y store for chunk c-1 ----
        if (c > 0) {
            unsigned y01 = cvtpk(ydef[0], ydef[1]);
            unsigned y23 = cvtpk(ydef[2], ydef[3]);
            u16* yp = ybf + (size_t)(rowbase - CHUNK + 16 * w + fq * 4) * D_SSM + pbase + fm;
            yp[0] = (u16)y01;
            yp[D_SSM] = (u16)(y01 >> 16);
            yp[2 * D_SSM] = (u16)y23;
            yp[3 * D_SSM] = (u16)(y23 >> 16);
        }

        // ---- next-chunk prefetch (C, CB rows; B-tile; x-tile; dt) ----
        bf16x8 afr_n[4] = {};
        f4 cbr_n[2][2] = {};
        uint4 bv0 = {}, bv1 = {}, bv2 = {}, bv3 = {};
        ushort4 xv = {0, 0, 0, 0};
        float dtv = 0.f;
        if (c < 63) {
            const u16* rowp1 = rowp + (size_t)CHUNK * CONV_DIM;
            const u16* Cg = rowp1 + (size_t)yl * CONV_DIM + D_SSM + D_STATE;
#pragma unroll
            for (int kk = 0; kk < 4; ++kk) afr_n[kk] = *(const bf16x8*)(Cg + kk * 32 + fk);
            const float* CBrow = CBbase + (size_t)(c + 1) * 4096 + yl * 64;
#pragma unroll
            for (int kk = 0; kk < 2; ++kk) {
                cbr_n[kk][0] = *(const f4*)&CBrow[kk * 32 + fk];
                cbr_n[kk][1] = *(const f4*)&CBrow[kk * 32 + fk + 4];
            }
            const u16* bp = rowp1 + D_SSM + no * 8;
            bv0 = *(const uint4*)(bp + (size_t)(4 * lq + 0) * CONV_DIM);
            bv1 = *(const uint4*)(bp + (size_t)(4 * lq + 1) * CONV_DIM);
            bv2 = *(const uint4*)(bp + (size_t)(4 * lq + 2) * CONV_DIM);
            bv3 = *(const uint4*)(bp + (size_t)(4 * lq + 3) * CONV_DIM);
            xv = *(const ushort4*)(rowp1 + (size_t)sl * CONV_DIM + pbase + sq * 4);
            if (t < 64) dtv = dtp[(size_t)(rowbase + CHUNK + t) * 64 + h];
        }

        const float* sc = scal[cur];
        const u16* xTc = xT[cur];
        const u16* BTc = BT[cur];
        const u16* Sdc = Sd[cur];

        // ---- LDS register loads ----
        union { uint4 v; u16 us[8]; bf16x8 bv; } xx0, xx1;
        xx0.v = *(const uint4*)&xTc[fm * 72 + fk];
        xx1.v = *(const uint4*)&xTc[fm * 72 + 32 + fk];
        ushort4 xe = *(const ushort4*)&xTc[fm * 72 + 16 * w + fq * 4];
        f4 els4 = *(const f4*)&sc[192 + 16 * w + fq * 4];
        float acl = sc[64 + yl];
        float cd = sc[192 + 63];
        f4 ac00 = *(const f4*)&sc[64 + fk], ac01 = *(const f4*)&sc[64 + fk + 4];
        f4 ac10 = *(const f4*)&sc[96 + fk], ac11 = *(const f4*)&sc[96 + fk + 4];
        f4 dt00 = *(const f4*)&sc[fk], dt01 = *(const f4*)&sc[fk + 4];
        f4 dt10 = *(const f4*)&sc[32 + fk], dt11 = *(const f4*)&sc[32 + fk + 4];
        f4 w00 = *(const f4*)&sc[128 + fk], w01 = *(const f4*)&sc[128 + fk + 4];
        f4 w10 = *(const f4*)&sc[160 + fk], w11 = *(const f4*)&sc[160 + fk + 4];
        bf16x8 sdf0 = *(const bf16x8*)&Sdc[fm * 136 + fk];
        bf16x8 sdf1 = *(const bf16x8*)&Sdc[fm * 136 + 32 + fk];
        bf16x8 sdf2 = *(const bf16x8*)&Sdc[fm * 136 + 64 + fk];
        bf16x8 sdf3 = *(const bf16x8*)&Sdc[fm * 136 + 96 + fk];
        int pb0 = (fq ^ fm7) << 3;
        int pb1 = ((4 + fq) ^ fm7) << 3;
        bf16x8 btf00 = *(const bf16x8*)&BTc[btc0 + pb0];
        bf16x8 btf01 = *(const bf16x8*)&BTc[btc0 + 1024 + pb0];
        bf16x8 btf10 = *(const bf16x8*)&BTc[btc0 + pb1];
        bf16x8 btf11 = *(const bf16x8*)&BTc[btc0 + 1024 + pb1];

        // ---- Y_diag = G . x ----
        f32x4 ydia = {0.f, 0.f, 0.f, 0.f};
        {
            union { unsigned u[4]; bf16x8 v; } gu;
            float g[8];
#pragma unroll
            for (int j = 0; j < 4; ++j) {
                int s = fk + j;
                g[j] = (s <= yl) ? cbr[0][0][j] * fexp2(acl - ac00[j]) * dt00[j] : 0.f;
            }
#pragma unroll
            for (int j = 0; j < 4; ++j) {
                int s = fk + 4 + j;
                g[4 + j] = (s <= yl) ? cbr[0][1][j] * fexp2(acl - ac01[j]) * dt01[j] : 0.f;
            }
            gu.u[0] = cvtpk(g[0], g[1]);
            gu.u[1] = cvtpk(g[2], g[3]);
            gu.u[2] = cvtpk(g[4], g[5]);
            gu.u[3] = cvtpk(g[6], g[7]);
            ydia = __builtin_amdgcn_mfma_f32_16x16x32_bf16(gu.v, xx0.bv, ydia, 0, 0, 0);
#pragma unroll
            for (int j = 0; j < 4; ++j) {
                int s = 32 + fk + j;
                g[j] = (s <= yl) ? cbr[1][0][j] * fexp2(acl - ac10[j]) * dt10[j] : 0.f;
            }
#pragma unroll
            for (int j = 0; j < 4; ++j) {
                int s = 32 + fk + 4 + j;
                g[4 + j] = (s <= yl) ? cbr[1][1][j] * fexp2(acl - ac11[j]) * dt11[j] : 0.f;
            }
            gu.u[0] = cvtpk(g[0], g[1]);
            gu.u[1] = cvtpk(g[2], g[3]);
            gu.u[2] = cvtpk(g[4], g[5]);
            gu.u[3] = cvtpk(g[6], g[7]);
            ydia = __builtin_amdgcn_mfma_f32_16x16x32_bf16(gu.v, xx1.bv, ydia, 0, 0, 0);
        }

        // ---- state update: S = cd*S + (w.x)^T . B ----
        sacc[0] *= cd;
        sacc[1] *= cd;
        {
            union { unsigned u[4]; bf16x8 v; } au;
            float xf[8];
#pragma unroll
            for (int j = 0; j < 8; ++j) xf[j] = bf2f(xx0.us[j]);
            au.u[0] = cvtpk(xf[0] * w00[0], xf[1] * w00[1]);
            au.u[1] = cvtpk(xf[2] * w00[2], xf[3] * w00[3]);
            au.u[2] = cvtpk(xf[4] * w01[0], xf[5] * w01[1]);
            au.u[3] = cvtpk(xf[6] * w01[2], xf[7] * w01[3]);
            sacc[0] = __builtin_amdgcn_mfma_f32_16x16x32_bf16(au.v, btf00, sacc[0], 0, 0, 0);
            sacc[1] = __builtin_amdgcn_mfma_f32_16x16x32_bf16(au.v, btf01, sacc[1], 0, 0, 0);
#pragma unroll
            for (int j = 0; j < 8; ++j) xf[j] = bf2f(xx1.us[j]);
            au.u[0] = cvtpk(xf[0] * w10[0], xf[1] * w10[1]);
            au.u[1] = cvtpk(xf[2] * w10[2], xf[3] * w10[3]);
            au.u[2] = cvtpk(xf[4] * w11[0], xf[5] * w11[1]);
            au.u[3] = cvtpk(xf[6] * w11[2], xf[7] * w11[3]);
            sacc[0] = __builtin_amdgcn_mfma_f32_16x16x32_bf16(au.v, btf10, sacc[0], 0, 0, 0);
            sacc[1] = __builtin_amdgcn_mfma_f32_16x16x32_bf16(au.v, btf11, sacc[1], 0, 0, 0);
        }

        // ---- Y_off = C . S^T ----
        f32x4 yoff = {0.f, 0.f, 0.f, 0.f};
        yoff = __builtin_amdgcn_mfma_f32_16x16x32_bf16(afr[0], sdf0, yoff, 0, 0, 0);
        yoff = __builtin_amdgcn_mfma_f32_16x16x32_bf16(afr[1], sdf1, yoff, 0, 0, 0);
        yoff = __builtin_amdgcn_mfma_f32_16x16x32_bf16(afr[2], sdf2, yoff, 0, 0, 0);
        yoff = __builtin_amdgcn_mfma_f32_16x16x32_bf16(afr[3], sdf3, yoff, 0, 0, 0);

        // ---- combine ----
        {
            float xf0 = bf2f(xe.x), xf1 = bf2f(xe.y), xf2 = bf2f(xe.z), xf3 = bf2f(xe.w);
            ydef[0] = yoff[0] * els4[0] + ydia[0] + Dh * xf0;
            ydef[1] = yoff[1] * els4[1] + ydia[1] + Dh * xf1;
            ydef[2] = yoff[2] * els4[2] + ydia[2] + Dh * xf2;
            ydef[3] = yoff[3] * els4[3] + ydia[3] + Dh * xf3;
        }

        // ---- write phase: stage chunk c+1 into buffers[nxt] ----
        if (c < 63) {
            int nxt = cur ^ 1;
            if (t < 64) {
                float v = dtv * Ah2;
#pragma unroll
                for (int off = 1; off < 64; off <<= 1) {
                    float pv = __shfl_up(v, off, 64);
                    if (t >= off) v += pv;
                }
                float alast = __shfl(v, 63, 64);
                scal[nxt][t] = dtv;
                scal[nxt][64 + t] = v;
                scal[nxt][128 + t] = dtv * fexp2(alast - v);
                scal[nxt][192 + t] = fexp2(v);
            }
            xT[nxt][(sq * 4 + 0) * 72 + sl] = xv.x;
            xT[nxt][(sq * 4 + 1) * 72 + sl] = xv.y;
            xT[nxt][(sq * 4 + 2) * 72 + sl] = xv.z;
            xT[nxt][(sq * 4 + 3) * 72 + sl] = xv.w;
            {
                union { uint4 v; unsigned ww[4]; } q0, q1, q2, q3;
                q0.v = bv0; q1.v = bv1; q2.v = bv2; q3.v = bv3;
                int base = no * 512 + (lq & 1) * 4;
                int lqh = lq >> 1;
#pragma unroll
                for (int j = 0; j < 8; ++j) {
                    unsigned sel = (j & 1) ? 0x07060302u : 0x05040100u;
                    uint2 pk;
                    pk.x = __builtin_amdgcn_perm(q1.ww[j >> 1], q0.ww[j >> 1], sel);
                    pk.y = __builtin_amdgcn_perm(q3.ww[j >> 1], q2.ww[j >> 1], sel);
                    *(uint2*)&BT[nxt][base + j * 64 + ((lqh ^ j) << 3)] = pk;
                }
            }
#pragma unroll
            for (int nt = 0; nt < 2; ++nt) {
                unsigned p01 = cvtpk(sacc[nt][0], sacc[nt][1]);
                unsigned p23 = cvtpk(sacc[nt][2], sacc[nt][3]);
                int colb = 32 * w + 16 * nt + fm;
                Sd[nxt][(fq * 4 + 0) * 136 + colb] = (u16)p01;
                Sd[nxt][(fq * 4 + 1) * 136 + colb] = (u16)(p01 >> 16);
                Sd[nxt][(fq * 4 + 2) * 136 + colb] = (u16)p23;
                Sd[nxt][(fq * 4 + 3) * 136 + colb] = (u16)(p23 >> 16);
            }
        }
        __syncthreads();

        // rotate prefetched operands
#pragma unroll
        for (int kk = 0; kk < 4; ++kk) afr[kk] = afr_n[kk];
#pragma unroll
        for (int kk = 0; kk < 2; ++kk) {
            cbr[kk][0] = cbr_n[kk][0];
            cbr[kk][1] = cbr_n[kk][1];
        }
    }

    // final deferred y store (chunk 63)
    {
        unsigned y01 = cvtpk(ydef[0], ydef[1]);
        unsigned y23 = cvtpk(ydef[2], ydef[3]);
        u16* yp = ybf + (size_t)(b * LTOT + 63 * CHUNK + 16 * w + fq * 4) * D_SSM + pbase + fm;
        yp[0] = (u16)y01;
        yp[D_SSM] = (u16)(y01 >> 16);
        yp[2 * D_SSM] = (u16)y23;
        yp[3 * D_SSM] = (u16)(y23 >> 16);
    }
}

// ---------------- gate (silu(z)) + RMSNorm, in-place on y_bf ----------------
__global__ __launch_bounds__(256) void gate_norm(const u16* __restrict__ zbf,
                                                 const float* __restrict__ normw,
                                                 u16* __restrict__ ybf) {
    int row = blockIdx.x, t = threadIdx.x;
    const uint2* y2 = (const uint2*)(ybf + (size_t)row * D_SSM);
    const uint2* z2 = (const uint2*)(zbf + (size_t)row * D_SSM);
    f4 yg[4];
    float ss = 0.f;
#pragma unroll
    for (int i = 0; i < 4; ++i) {
        int idx = i * 256 + t;
        uint2 yv = y2[idx], zv = z2[idx];
        float ya[4] = {bf2f(yv.x & 0xffffu), bf2f(yv.x >> 16), bf2f(yv.y & 0xffffu), bf2f(yv.y >> 16)};
        float za[4] = {bf2f(zv.x & 0xffffu), bf2f(zv.x >> 16), bf2f(zv.y & 0xffffu), bf2f(zv.y >> 16)};
        f4 g;
#pragma unroll
        for (int k = 0; k < 4; ++k) {
            float sz = za[k] / (1.f + __expf(-za[k]));
            g[k] = ya[k] * sz;
            ss += g[k] * g[k];
        }
        yg[i] = g;
    }
#pragma unroll
    for (int off = 32; off; off >>= 1) ss += __shfl_down(ss, off, 64);
    __shared__ float red[4];
    if ((t & 63) == 0) red[t >> 6] = ss;
    __syncthreads();
    float tot = red[0] + red[1] + red[2] + red[3];
    float scale = rsqrtf(tot / (float)D_SSM + 1e-5f);
    const f4* nw4 = (const f4*)normw;
    uint2* out = (uint2*)(ybf + (size_t)row * D_SSM);
#pragma unroll
    for (int i = 0; i < 4; ++i) {
        int idx = i * 256 + t;
        f4 v = yg[i] * scale * nw4[idx];
        uint2 pk;
        pk.x = pack2(v[0], v[1]);
        pk.y = pack2(v[2], v[3]);
        out[idx] = pk;
    }
}

// ---------------- launch ----------------
extern "C" void kernel_launch(void* const* d_in, const int* in_sizes, int n_in,
                              void* d_out, int out_size, void* d_ws, size_t ws_size,
                              hipStream_t stream) {
    const float* u = (const float*)d_in[0];
    const float* W_in = (const float*)d_in[1];
    const float* conv_w = (const float*)d_in[2];
    const float* conv_b = (const float*)d_in[3];
    const float* dt_bias = (const float*)d_in[4];
    const float* A_log = (const float*)d_in[5];
    const float* Dv = (const float*)d_in[6];
    const float* normw = (const float*)d_in[7];
    const float* W_out = (const float*)d_in[8];
    float* out = (float*)d_out;
    char* ws = (char*)d_ws;

    // workspace layout
    u16* z_bf = (u16*)(ws + 0ULL);              //  8192x4096 bf16 = 67,108,864
    u16* xbcdt = (u16*)(ws + 67108864ULL);      //  8192x4480 bf16 = 73,400,320
    u16* y_bf = xbcdt;                          //  overlay: 8192x4096 bf16
    u16* convO = (u16*)(ws + 140509184ULL);     //  8192x4352 bf16 = 71,303,168
    u16* u_bf = convO;                          //  overlay: 33,554,432
    u16* win_bf = (u16*)(ws + 174063616ULL);    //  overlay: 8704x2048 bf16 = 35,651,584
    u16* wout_bf = convO;                       //  overlay: 16,777,216 (after ssm)
    float* dtp = (float*)(ws + 211812352ULL);   //  8192x64 f32 = 2,097,152
    float* CBb = (float*)(ws + 213909504ULL);   //  128x64x64 f32 = 2,097,152

    tobf16_kernel<<<16384, 256, 0, stream>>>(u, u_bf, 4194304);
    winpad_kernel<<<17408, 256, 0, stream>>>(W_in, win_bf);
    gemm256<1><<<dim3(16, 32), 512, 0, stream>>>(u_bf, win_bf, z_bf, 2048, 4096, 4096);
    gemm256<1><<<dim3(18, 32), 512, 0, stream>>>(u_bf, win_bf + (size_t)4096 * 2048, xbcdt, 2048, XBC_LD, 4480);
    conv_kernel<<<dim3(17, 8192), 256, 0, stream>>>(xbcdt, conv_w, conv_b, convO);
    dt_kernel<<<2048, 256, 0, stream>>>(xbcdt, dt_bias, dtp);
    cb_kernel<<<128, 256, 0, stream>>>(convO, CBb);
    ssm_mfma<<<512, 256, 0, stream>>>(convO, dtp, CBb, A_log, Dv, y_bf);
    tobf16_kernel<<<8192, 256, 0, stream>>>(W_out, wout_bf, 2097152);
    gate_norm<<<8192, 256, 0, stream>>>(z_bf, normw, y_bf);
    gemm256<0><<<dim3(8, 32), 512, 0, stream>>>(y_bf, wout_bf, out, 4096, 2048, 2048);
}

// Round 6
// 855.149 us; speedup vs baseline: 1.3249x; 1.1374x over previous
//
#include <hip/hip_runtime.h>

typedef unsigned short u16;
typedef __attribute__((ext_vector_type(4))) float f4;
typedef __attribute__((ext_vector_type(8))) __bf16 bf16x8;
typedef __attribute__((ext_vector_type(4))) float f32x4;

#define D_MODEL 2048
#define D_SSM 4096
#define D_STATE 128
#define NHEADS 64
#define HEADDIM 64
#define CHUNK 64
#define LTOT 4096
#define NB 2
#define CONV_DIM 4352
#define XBC_LD 4480   // 4352 conv channels + 64 dt + 64 pad
#define LOG2E 1.4426950408889634f

__device__ inline float bf2f(unsigned v) { return __uint_as_float(v << 16); }
__device__ inline u16 f2bf(float f) {
    unsigned u = __float_as_uint(f);
    unsigned r = (u + 0x7fffu + ((u >> 16) & 1u)) >> 16;
    return (u16)r;
}
__device__ inline unsigned pack2(float a, float b) {
    return (unsigned)f2bf(a) | ((unsigned)f2bf(b) << 16);
}
// raw v_exp_f32: input in log2 domain
__device__ inline float fexp2(float x) {
    float r;
    asm("v_exp_f32 %0, %1" : "=v"(r) : "v"(x));
    return r;
}
// packed f32x2 -> bf16x2 (RNE), one instruction
__device__ inline unsigned cvtpk(float lo, float hi) {
    unsigned r;
    asm("v_cvt_pk_bf16_f32 %0, %1, %2" : "=v"(r) : "v"(lo), "v"(hi));
    return r;
}
__device__ inline void gload_lds16(const void* g, void* l) {
    __builtin_amdgcn_global_load_lds((const __attribute__((address_space(1))) void*)g,
                                     (__attribute__((address_space(3))) void*)l, 16, 0, 0);
}
__device__ inline f32x4 mfma16(bf16x8 a, bf16x8 b, f32x4 c) {
    return __builtin_amdgcn_mfma_f32_16x16x32_bf16(a, b, c, 0, 0, 0);
}

// ---------------- f32 -> bf16 cast ----------------
__global__ __launch_bounds__(256) void tobf16_kernel(const float* __restrict__ src,
                                                     u16* __restrict__ dst, int n4) {
    int i = blockIdx.x * 256 + threadIdx.x;
    if (i < n4) {
        f4 v = ((const f4*)src)[i];
        uint2 pk;
        pk.x = pack2(v[0], v[1]);
        pk.y = pack2(v[2], v[3]);
        ((uint2*)dst)[i] = pk;
    }
}

// W_in (8512 x 2048) f32 -> win_bf (8704 x 2048) bf16, pad rows zero
__global__ __launch_bounds__(256) void winpad_kernel(const float* __restrict__ src,
                                                     u16* __restrict__ dst) {
    int i = blockIdx.x * 256 + threadIdx.x;
    if (i >= (8704 * 2048 / 4)) return;
    int col4 = i & 511;
    int row = i >> 9;
    f4 v = {0.f, 0.f, 0.f, 0.f};
    if (row < 8512) v = ((const f4*)src)[row * 512 + col4];
    uint2 pk;
    pk.x = pack2(v[0], v[1]);
    pk.y = pack2(v[2], v[3]);
    ((uint2*)dst)[i] = pk;
}

// ---------------- GEMM 256x256, 8-phase counted-vmcnt schedule --------------------
// C[m,n] = sum_k A[m,k]*B[n,k]; bf16 in. 512 thr = 8 waves (2M x 4N).
// XCD mapping (L2-locality): m = xcd*4 + (s&3), n = s>>2 — each XCD owns 4 fixed
// M-rows (A panels L2-resident) and the 4 m-uses of each B panel are temporally
// adjacent (B read ~once per XCD from L3). Uniform: nwg = ncols*32, %8 == 0 always.
// Phases read {A-half(q>=2), B-half(q&1)}; B0-frags retained across p0->p2.
// Counted waits before end-of-phase barrier: vmcnt(6) @p0, vmcnt(8) @p3.
// MODE 0: f32 out (Cp, ldC). MODE 2: bf16 split out — cols<4096 -> Cp (ld 4096),
// cols>=4096 -> Cp2 (ld 4480, guard col<8576).
template <int MODE>
__global__ __launch_bounds__(512, 1) void gemm256(const u16* __restrict__ A,
                                                  const u16* __restrict__ Bm,
                                                  void* __restrict__ Cp,
                                                  void* __restrict__ Cp2,
                                                  int K, int ldC, int Nreal) {
    __shared__ __align__(16) u16 lds[2][32768];  // per buf: A[0,16384) | B[16384,32768)

    int t = threadIdx.x;
    int w = t >> 6, lane = t & 63;
    int fm = lane & 15, fq = lane >> 4;
    int wm = w >> 2, wn = w & 3;

    // M-affine XCD mapping (gridDim.x = ncols, gridDim.y = 32 M-blocks)
    int orig = blockIdx.y * gridDim.x + blockIdx.x;
    int xcd = orig & 7, s = orig >> 3;
    int blockM = (xcd * 4 + (s & 3)) * 256;
    int blockN = (s >> 2) * 256;

    // staging map: thread t loads 16B; LDS dest linear; global source pre-swizzled.
    int srow = t >> 3;
    int scol = (((t & 7) ^ (srow & 7)) << 3);
    const u16* Asrc = A + (size_t)(blockM + srow) * K + scol;
    const u16* Bsrc = Bm + (size_t)(blockN + srow) * K + scol;

#define STAGE(buf, isB, half, tile)                                              \
    do {                                                                         \
        const u16* _s = ((isB) ? Bsrc : Asrc) + (size_t)(tile) * 64 +            \
                        (size_t)((half) * 128) * K;                              \
        u16* _d = &lds[buf][(isB) * 16384 + (half) * 8192 + t * 8];              \
        gload_lds16(_s, _d);                                                     \
        gload_lds16(_s + (size_t)64 * K, _d + 4096);                             \
    } while (0)

    int nt = K >> 6;
    // prologue issue order: A0(0),B0(0),A1(0),B1(0),A0(1),B0(1)
    STAGE(0, 0, 0, 0); STAGE(0, 1, 0, 0);
    STAGE(0, 0, 1, 0); STAGE(0, 1, 1, 0);
    STAGE(1, 0, 0, 1); STAGE(1, 1, 0, 1);

    f32x4 acc[8][4] = {};
    int lro = fm * 64;
    int ko0 = ((fq ^ (fm & 7)) << 3);        // swizzled 16B-block, kstep 0
    int ko1 = (((4 + fq) ^ (fm & 7)) << 3);  // kstep 1

    asm volatile("s_waitcnt vmcnt(8)" ::: "memory");
    __builtin_amdgcn_s_barrier();

    for (int kt = 0; kt < nt; ++kt) {
        int d = kt & 1, e = d ^ 1;
        const u16* aH0 = &lds[d][wm * 4096 + lro];
        const u16* aH1 = aH0 + 8192;
        const u16* bH0 = &lds[d][16384 + wn * 2048 + lro];
        const u16* bH1 = bH0 + 8192;
        bf16x8 af[4][2], b0[2][2], b1[2][2];

        // ---------------- phase 0: M0-3 x N0-1 (loads A0, B0; B0 retained) --------
#pragma unroll
        for (int i = 0; i < 4; ++i) {
            af[i][0] = *(const bf16x8*)(aH0 + i * 1024 + ko0);
            af[i][1] = *(const bf16x8*)(aH0 + i * 1024 + ko1);
        }
#pragma unroll
        for (int j = 0; j < 2; ++j) {
            b0[j][0] = *(const bf16x8*)(bH0 + j * 1024 + ko0);
            b0[j][1] = *(const bf16x8*)(bH0 + j * 1024 + ko1);
        }
        if (kt + 1 < nt) STAGE(e, 0, 1, kt + 1);
        __builtin_amdgcn_s_barrier();
        __builtin_amdgcn_s_setprio(1);
#pragma unroll
        for (int i = 0; i < 4; ++i)
#pragma unroll
            for (int j = 0; j < 2; ++j) {
                acc[i][j] = mfma16(af[i][0], b0[j][0], acc[i][j]);
                acc[i][j] = mfma16(af[i][1], b0[j][1], acc[i][j]);
            }
        __builtin_amdgcn_s_setprio(0);
        if (kt == nt - 1) asm volatile("s_waitcnt vmcnt(0)" ::: "memory");
        else              asm volatile("s_waitcnt vmcnt(6)" ::: "memory");
        __builtin_amdgcn_s_barrier();

        // ---------------- phase 1: M0-3 x N2-3 (loads B1) ----------------
#pragma unroll
        for (int j = 0; j < 2; ++j) {
            b1[j][0] = *(const bf16x8*)(bH1 + j * 1024 + ko0);
            b1[j][1] = *(const bf16x8*)(bH1 + j * 1024 + ko1);
        }
        if (kt + 1 < nt) STAGE(e, 1, 1, kt + 1);
        __builtin_amdgcn_s_barrier();
        __builtin_amdgcn_s_setprio(1);
#pragma unroll
        for (int i = 0; i < 4; ++i)
#pragma unroll
            for (int j = 0; j < 2; ++j) {
                acc[i][2 + j] = mfma16(af[i][0], b1[j][0], acc[i][2 + j]);
                acc[i][2 + j] = mfma16(af[i][1], b1[j][1], acc[i][2 + j]);
            }
        __builtin_amdgcn_s_setprio(0);
        __builtin_amdgcn_s_barrier();

        // ---------------- phase 2: M4-7 x N0-1 (loads A1; reuses b0 regs) ---------
#pragma unroll
        for (int i = 0; i < 4; ++i) {
            af[i][0] = *(const bf16x8*)(aH1 + i * 1024 + ko0);
            af[i][1] = *(const bf16x8*)(aH1 + i * 1024 + ko1);
        }
        if (kt + 2 < nt) STAGE(d, 0, 0, kt + 2);
        __builtin_amdgcn_s_barrier();
        __builtin_amdgcn_s_setprio(1);
#pragma unroll
        for (int i = 0; i < 4; ++i)
#pragma unroll
            for (int j = 0; j < 2; ++j) {
                acc[4 + i][j] = mfma16(af[i][0], b0[j][0], acc[4 + i][j]);
                acc[4 + i][j] = mfma16(af[i][1], b0[j][1], acc[4 + i][j]);
            }
        __builtin_amdgcn_s_setprio(0);
        __builtin_amdgcn_s_barrier();

        // ---------------- phase 3: M4-7 x N2-3 (reuses b1 regs) ----------------
        if (kt + 2 < nt) STAGE(d, 1, 0, kt + 2);
        __builtin_amdgcn_s_barrier();
        __builtin_amdgcn_s_setprio(1);
#pragma unroll
        for (int i = 0; i < 4; ++i)
#pragma unroll
            for (int j = 0; j < 2; ++j) {
                acc[4 + i][2 + j] = mfma16(af[i][0], b1[j][0], acc[4 + i][2 + j]);
                acc[4 + i][2 + j] = mfma16(af[i][1], b1[j][1], acc[4 + i][2 + j]);
            }
        __builtin_amdgcn_s_setprio(0);
        if (kt == nt - 2)      asm volatile("s_waitcnt vmcnt(4)" ::: "memory");
        else if (kt < nt - 2)  asm volatile("s_waitcnt vmcnt(8)" ::: "memory");
        __builtin_amdgcn_s_barrier();
    }
#undef STAGE

    // epilogue
    u16* Cb16 = 0;
    int ldb = 0, coff = 0;
    if (MODE == 2) {
        if (blockN < 4096) { Cb16 = (u16*)Cp;  ldb = 4096; coff = blockN; }
        else               { Cb16 = (u16*)Cp2; ldb = 4480; coff = blockN - 4096; }
    }
#pragma unroll
    for (int i = 0; i < 8; ++i) {
        int rbase = (i < 4) ? (wm * 64 + i * 16) : (128 + wm * 64 + (i - 4) * 16);
        int row = blockM + rbase + fq * 4;
#pragma unroll
        for (int j = 0; j < 4; ++j) {
            int cbase = (j < 2) ? (wn * 32 + j * 16) : (128 + wn * 32 + (j - 2) * 16);
            if (MODE == 2) {
                int col = coff + cbase + fm;
                if (col < ldb) {
#pragma unroll
                    for (int r = 0; r < 4; ++r)
                        Cb16[(size_t)(row + r) * ldb + col] = f2bf(acc[i][j][r]);
                }
            } else {
                int col = blockN + cbase + fm;
                if (col < Nreal) {
                    float* C = (float*)Cp;
#pragma unroll
                    for (int r = 0; r < 4; ++r)
                        C[(size_t)(row + r) * ldC + col] = acc[i][j][r];
                }
            }
        }
    }
}

// ---------------- depthwise causal conv(4) + bias + silu; bf16 in/out --------------
// thread = 1 channel x 8 L-positions: 11 row-loads -> 8 outputs (was 4 loads/output)
__global__ __launch_bounds__(256) void conv_kernel(const u16* __restrict__ xbcdt,
                                                   const float* __restrict__ conv_w,
                                                   const float* __restrict__ conv_b,
                                                   u16* __restrict__ convO) {
    int ch = blockIdx.x * 256 + threadIdx.x;  // 17*256 = 4352 exact
    int r0 = blockIdx.y * 8;                  // 1024 row-groups over 8192 rows
    int l0 = r0 & (LTOT - 1);
    f4 wv = *(const f4*)&conv_w[ch * 4];
    float bias = conv_b[ch];
    float xv[11];
#pragma unroll
    for (int j = 0; j < 11; ++j) {
        int dj = j - 3;
        xv[j] = (l0 + dj >= 0) ? bf2f(xbcdt[(size_t)(r0 + dj) * XBC_LD + ch]) : 0.f;
    }
#pragma unroll
    for (int i = 0; i < 8; ++i) {
        float acc = bias + xv[i] * wv[0] + xv[i + 1] * wv[1] + xv[i + 2] * wv[2] + xv[i + 3] * wv[3];
        convO[(size_t)(r0 + i) * CONV_DIM + ch] = f2bf(acc / (1.f + __expf(-acc)));
    }
}

// ---------------- dt = softplus(raw + bias) -> dtp[row][h] f32 ----------------
__global__ __launch_bounds__(256) void dt_kernel(const u16* __restrict__ xbcdt,
                                                 const float* __restrict__ dt_bias,
                                                 float* __restrict__ dtp) {
    int idx = blockIdx.x * 256 + threadIdx.x;
    if (idx >= NB * LTOT * NHEADS) return;
    int row = idx >> 6, h = idx & 63;
    float x = bf2f(xbcdt[(size_t)row * XBC_LD + CONV_DIM + h]) + dt_bias[h];
    dtp[idx] = (x > 15.f) ? x : log1pf(__expf(x));
}

// ---------------- CB[l,s] = sum_n C[l,n]*B[s,n] per (b,c) -> CBb f32 ----------------
__global__ __launch_bounds__(256) void cb_kernel(const u16* __restrict__ convO,
                                                 float* __restrict__ CBb) {
    __shared__ u16 Bt[128 * 68];  // [n][s]
    __shared__ u16 Ct[128 * 68];  // [n][l]
    int bc = blockIdx.x;
    int c = bc & 63, b = bc >> 6;
    int rowbase = b * LTOT + c * CHUNK;
    int t = threadIdx.x;
#pragma unroll
    for (int i = 0; i < 32; i++) {
        int idx = i * 256 + t;
        int s = idx >> 7, n = idx & 127;
        Bt[n * 68 + s] = convO[(size_t)(rowbase + s) * CONV_DIM + D_SSM + n];
        Ct[n * 68 + s] = convO[(size_t)(rowbase + s) * CONV_DIM + D_SSM + D_STATE + n];
    }
    __syncthreads();
    int sq = t & 15, lq = t >> 4;
    f4 acc[4] = {};
#pragma unroll 4
    for (int n = 0; n < 128; n++) {
        ushort4 bv = *(const ushort4*)&Bt[n * 68 + sq * 4];
        ushort4 cv = *(const ushort4*)&Ct[n * 68 + lq * 4];
        f4 bf;
        bf[0] = bf2f(bv.x); bf[1] = bf2f(bv.y); bf[2] = bf2f(bv.z); bf[3] = bf2f(bv.w);
        float c0 = bf2f(cv.x), c1 = bf2f(cv.y), c2 = bf2f(cv.z), c3 = bf2f(cv.w);
        acc[0] += c0 * bf; acc[1] += c1 * bf; acc[2] += c2 * bf; acc[3] += c3 * bf;
    }
    float* outb = CBb + (size_t)bc * 4096;
#pragma unroll
    for (int j = 0; j < 4; j++) *(f4*)&outb[(lq * 4 + j) * 64 + sq * 4] = acc[j];
}

// ---------------- fused SSM (deep-prefetch pipeline, low-issue-count version) -------
__global__ __launch_bounds__(256, 2) void ssm_mfma(const u16* __restrict__ convO,
                                                   const float* __restrict__ dtp,
                                                   const float* __restrict__ CBb,
                                                   const float* __restrict__ A_log,
                                                   const float* __restrict__ Dvec,
                                                   u16* __restrict__ ybf) {
    __shared__ __align__(16) u16 xT[2][16 * 72];    // [p'][l]
    __shared__ __align__(16) u16 BT[2][128 * 64];   // [n][l swizzled 16B blocks]
    __shared__ __align__(16) u16 Sd[2][16 * 136];   // [p'][n]
    __shared__ __align__(16) float scal[2][256];    // dts | acs(log2) | wls | els

    int t = threadIdx.x;
    int w = t >> 6, lane = t & 63;
    int z = blockIdx.x;
    int pg = z & 3, h = (z >> 2) & 63, b = z >> 8;
    int pbase = h * 64 + pg * 16;
    float Ah2 = -__expf(A_log[h]) * LOG2E;  // log2-domain decay rate
    float Dh = Dvec[h];

    int fm = lane & 15;        // within-tile row/col index
    int fq = lane >> 4;        // quad 0..3
    int fk = fq * 8;           // k-base within a 32-wide k-step
    int sl = t & 63;           // xT staging: row l
    int sq = t >> 6;           // xT staging: quarter
    int lq = t & 15;           // BT staging: l-quad (rows 4lq..4lq+3)
    int no = t >> 4;           // BT staging: n-octet (cols no*8..no*8+7)

    f32x4 sacc[2] = {};        // state acc: element (p' = fq*4+r, n = 32w+16nt+fm)

    const float* CBbase = CBb + (size_t)(b * 64) * 4096;
    int yl = 16 * w + fm;      // A-operand row l for Y mfmas
    int btc0 = (32 * w + fm) * 64;          // BT col base, nt=0
    int fm7 = fm & 7;

    // ---------- prologue: stage chunk 0 into buffers[0]; load operands for chunk 0 ----
    bf16x8 afr[4];             // C rows for current chunk (loaded one iter ahead)
    f4 cbr[2][2];              // CB rows for current chunk
    {
        int rowbase = b * LTOT;
        const u16* rowp = convO + (size_t)rowbase * CONV_DIM;
        const u16* Cg = rowp + (size_t)yl * CONV_DIM + D_SSM + D_STATE;
#pragma unroll
        for (int kk = 0; kk < 4; ++kk) afr[kk] = *(const bf16x8*)(Cg + kk * 32 + fk);
        const float* CBrow = CBbase + yl * 64;
#pragma unroll
        for (int kk = 0; kk < 2; ++kk) {
            cbr[kk][0] = *(const f4*)&CBrow[kk * 32 + fk];
            cbr[kk][1] = *(const f4*)&CBrow[kk * 32 + fk + 4];
        }
        if (t < 64) {
            float dtv = dtp[(size_t)(rowbase + t) * 64 + h];
            float v = dtv * Ah2;
#pragma unroll
            for (int off = 1; off < 64; off <<= 1) {
                float pv = __shfl_up(v, off, 64);
                if (t >= off) v += pv;
            }
            float alast = __shfl(v, 63, 64);
            scal[0][t] = dtv;
            scal[0][64 + t] = v;
            scal[0][128 + t] = dtv * fexp2(alast - v);
            scal[0][192 + t] = fexp2(v);
        }
        ushort4 xv = *(const ushort4*)(rowp + (size_t)sl * CONV_DIM + pbase + sq * 4);
        xT[0][(sq * 4 + 0) * 72 + sl] = xv.x;
        xT[0][(sq * 4 + 1) * 72 + sl] = xv.y;
        xT[0][(sq * 4 + 2) * 72 + sl] = xv.z;
        xT[0][(sq * 4 + 3) * 72 + sl] = xv.w;
        {   // BT[0] staging
            const u16* bp = rowp + D_SSM + no * 8;
            union { uint4 v; unsigned ww[4]; } q[4];
#pragma unroll
            for (int r = 0; r < 4; ++r) q[r].v = *(const uint4*)(bp + (size_t)(4 * lq + r) * CONV_DIM);
            int base = no * 512 + (lq & 1) * 4;
            int lqh = lq >> 1;
#pragma unroll
            for (int j = 0; j < 8; ++j) {
                unsigned sel = (j & 1) ? 0x07060302u : 0x05040100u;
                uint2 pk;
                pk.x = __builtin_amdgcn_perm(q[1].ww[j >> 1], q[0].ww[j >> 1], sel);
                pk.y = __builtin_amdgcn_perm(q[3].ww[j >> 1], q[2].ww[j >> 1], sel);
                *(uint2*)&BT[0][base + j * 64 + ((lqh ^ j) << 3)] = pk;
            }
        }
#pragma unroll
        for (int nt = 0; nt < 2; ++nt)
#pragma unroll
            for (int r = 0; r < 4; ++r)
                Sd[0][(fq * 4 + r) * 136 + 32 * w + 16 * nt + fm] = 0;
        __syncthreads();
    }

    f4 ydef = {0.f, 0.f, 0.f, 0.f};   // deferred y values for chunk c-1
    int cur = 0;
    for (int c = 0; c < 64; ++c, cur ^= 1) {
        int rowbase = b * LTOT + c * CHUNK;
        const u16* rowp = convO + (size_t)rowbase * CONV_DIM;

        // ---- deferred y store for chunk c-1 ----
        if (c > 0) {
            unsigned y01 = cvtpk(ydef[0], ydef[1]);
            unsigned y23 = cvtpk(ydef[2], ydef[3]);
            u16* yp = ybf + (size_t)(rowbase - CHUNK + 16 * w + fq * 4) * D_SSM + pbase + fm;
            yp[0] = (u16)y01;
            yp[D_SSM] = (u16)(y01 >> 16);
            yp[2 * D_SSM] = (u16)y23;
            yp[3 * D_SSM] = (u16)(y23 >> 16);
        }

        // ---- next-chunk prefetch (C, CB rows; B-tile; x-tile; dt) ----
        bf16x8 afr_n[4] = {};
        f4 cbr_n[2][2] = {};
        uint4 bv0 = {}, bv1 = {}, bv2 = {}, bv3 = {};
        ushort4 xv = {0, 0, 0, 0};
        float dtv = 0.f;
        if (c < 63) {
            const u16* rowp1 = rowp + (size_t)CHUNK * CONV_DIM;
            const u16* Cg = rowp1 + (size_t)yl * CONV_DIM + D_SSM + D_STATE;
#pragma unroll
            for (int kk = 0; kk < 4; ++kk) afr_n[kk] = *(const bf16x8*)(Cg + kk * 32 + fk);
            const float* CBrow = CBbase + (size_t)(c + 1) * 4096 + yl * 64;
#pragma unroll
            for (int kk = 0; kk < 2; ++kk) {
                cbr_n[kk][0] = *(const f4*)&CBrow[kk * 32 + fk];
                cbr_n[kk][1] = *(const f4*)&CBrow[kk * 32 + fk + 4];
            }
            const u16* bp = rowp1 + D_SSM + no * 8;
            bv0 = *(const uint4*)(bp + (size_t)(4 * lq + 0) * CONV_DIM);
            bv1 = *(const uint4*)(bp + (size_t)(4 * lq + 1) * CONV_DIM);
            bv2 = *(const uint4*)(bp + (size_t)(4 * lq + 2) * CONV_DIM);
            bv3 = *(const uint4*)(bp + (size_t)(4 * lq + 3) * CONV_DIM);
            xv = *(const ushort4*)(rowp1 + (size_t)sl * CONV_DIM + pbase + sq * 4);
            if (t < 64) dtv = dtp[(size_t)(rowbase + CHUNK + t) * 64 + h];
        }

        const float* sc = scal[cur];
        const u16* xTc = xT[cur];
        const u16* BTc = BT[cur];
        const u16* Sdc = Sd[cur];

        // ---- LDS register loads ----
        union { uint4 v; u16 us[8]; bf16x8 bv; } xx0, xx1;
        xx0.v = *(const uint4*)&xTc[fm * 72 + fk];
        xx1.v = *(const uint4*)&xTc[fm * 72 + 32 + fk];
        ushort4 xe = *(const ushort4*)&xTc[fm * 72 + 16 * w + fq * 4];
        f4 els4 = *(const f4*)&sc[192 + 16 * w + fq * 4];
        float acl = sc[64 + yl];
        float cd = sc[192 + 63];
        f4 ac00 = *(const f4*)&sc[64 + fk], ac01 = *(const f4*)&sc[64 + fk + 4];
        f4 ac10 = *(const f4*)&sc[96 + fk], ac11 = *(const f4*)&sc[96 + fk + 4];
        f4 dt00 = *(const f4*)&sc[fk], dt01 = *(const f4*)&sc[fk + 4];
        f4 dt10 = *(const f4*)&sc[32 + fk], dt11 = *(const f4*)&sc[32 + fk + 4];
        f4 w00 = *(const f4*)&sc[128 + fk], w01 = *(const f4*)&sc[128 + fk + 4];
        f4 w10 = *(const f4*)&sc[160 + fk], w11 = *(const f4*)&sc[160 + fk + 4];
        bf16x8 sdf0 = *(const bf16x8*)&Sdc[fm * 136 + fk];
        bf16x8 sdf1 = *(const bf16x8*)&Sdc[fm * 136 + 32 + fk];
        bf16x8 sdf2 = *(const bf16x8*)&Sdc[fm * 136 + 64 + fk];
        bf16x8 sdf3 = *(const bf16x8*)&Sdc[fm * 136 + 96 + fk];
        int pb0 = (fq ^ fm7) << 3;
        int pb1 = ((4 + fq) ^ fm7) << 3;
        bf16x8 btf00 = *(const bf16x8*)&BTc[btc0 + pb0];
        bf16x8 btf01 = *(const bf16x8*)&BTc[btc0 + 1024 + pb0];
        bf16x8 btf10 = *(const bf16x8*)&BTc[btc0 + pb1];
        bf16x8 btf11 = *(const bf16x8*)&BTc[btc0 + 1024 + pb1];

        // ---- Y_diag = G . x ----
        f32x4 ydia = {0.f, 0.f, 0.f, 0.f};
        {
            union { unsigned u[4]; bf16x8 v; } gu;
            float g[8];
#pragma unroll
            for (int j = 0; j < 4; ++j) {
                int s = fk + j;
                g[j] = (s <= yl) ? cbr[0][0][j] * fexp2(acl - ac00[j]) * dt00[j] : 0.f;
            }
#pragma unroll
            for (int j = 0; j < 4; ++j) {
                int s = fk + 4 + j;
                g[4 + j] = (s <= yl) ? cbr[0][1][j] * fexp2(acl - ac01[j]) * dt01[j] : 0.f;
            }
            gu.u[0] = cvtpk(g[0], g[1]);
            gu.u[1] = cvtpk(g[2], g[3]);
            gu.u[2] = cvtpk(g[4], g[5]);
            gu.u[3] = cvtpk(g[6], g[7]);
            ydia = __builtin_amdgcn_mfma_f32_16x16x32_bf16(gu.v, xx0.bv, ydia, 0, 0, 0);
#pragma unroll
            for (int j = 0; j < 4; ++j) {
                int s = 32 + fk + j;
                g[j] = (s <= yl) ? cbr[1][0][j] * fexp2(acl - ac10[j]) * dt10[j] : 0.f;
            }
#pragma unroll
            for (int j = 0; j < 4; ++j) {
                int s = 32 + fk + 4 + j;
                g[4 + j] = (s <= yl) ? cbr[1][1][j] * fexp2(acl - ac11[j]) * dt11[j] : 0.f;
            }
            gu.u[0] = cvtpk(g[0], g[1]);
            gu.u[1] = cvtpk(g[2], g[3]);
            gu.u[2] = cvtpk(g[4], g[5]);
            gu.u[3] = cvtpk(g[6], g[7]);
            ydia = __builtin_amdgcn_mfma_f32_16x16x32_bf16(gu.v, xx1.bv, ydia, 0, 0, 0);
        }

        // ---- state update: S = cd*S + (w.x)^T . B ----
        sacc[0] *= cd;
        sacc[1] *= cd;
        {
            union { unsigned u[4]; bf16x8 v; } au;
            float xf[8];
#pragma unroll
            for (int j = 0; j < 8; ++j) xf[j] = bf2f(xx0.us[j]);
            au.u[0] = cvtpk(xf[0] * w00[0], xf[1] * w00[1]);
            au.u[1] = cvtpk(xf[2] * w00[2], xf[3] * w00[3]);
            au.u[2] = cvtpk(xf[4] * w01[0], xf[5] * w01[1]);
            au.u[3] = cvtpk(xf[6] * w01[2], xf[7] * w01[3]);
            sacc[0] = __builtin_amdgcn_mfma_f32_16x16x32_bf16(au.v, btf00, sacc[0], 0, 0, 0);
            sacc[1] = __builtin_amdgcn_mfma_f32_16x16x32_bf16(au.v, btf01, sacc[1], 0, 0, 0);
#pragma unroll
            for (int j = 0; j < 8; ++j) xf[j] = bf2f(xx1.us[j]);
            au.u[0] = cvtpk(xf[0] * w10[0], xf[1] * w10[1]);
            au.u[1] = cvtpk(xf[2] * w10[2], xf[3] * w10[3]);
            au.u[2] = cvtpk(xf[4] * w11[0], xf[5] * w11[1]);
            au.u[3] = cvtpk(xf[6] * w11[2], xf[7] * w11[3]);
            sacc[0] = __builtin_amdgcn_mfma_f32_16x16x32_bf16(au.v, btf10, sacc[0], 0, 0, 0);
            sacc[1] = __builtin_amdgcn_mfma_f32_16x16x32_bf16(au.v, btf11, sacc[1], 0, 0, 0);
        }

        // ---- Y_off = C . S^T ----
        f32x4 yoff = {0.f, 0.f, 0.f, 0.f};
        yoff = __builtin_amdgcn_mfma_f32_16x16x32_bf16(afr[0], sdf0, yoff, 0, 0, 0);
        yoff = __builtin_amdgcn_mfma_f32_16x16x32_bf16(afr[1], sdf1, yoff, 0, 0, 0);
        yoff = __builtin_amdgcn_mfma_f32_16x16x32_bf16(afr[2], sdf2, yoff, 0, 0, 0);
        yoff = __builtin_amdgcn_mfma_f32_16x16x32_bf16(afr[3], sdf3, yoff, 0, 0, 0);

        // ---- combine ----
        {
            float xf0 = bf2f(xe.x), xf1 = bf2f(xe.y), xf2 = bf2f(xe.z), xf3 = bf2f(xe.w);
            ydef[0] = yoff[0] * els4[0] + ydia[0] + Dh * xf0;
            ydef[1] = yoff[1] * els4[1] + ydia[1] + Dh * xf1;
            ydef[2] = yoff[2] * els4[2] + ydia[2] + Dh * xf2;
            ydef[3] = yoff[3] * els4[3] + ydia[3] + Dh * xf3;
        }

        // ---- write phase: stage chunk c+1 into buffers[nxt] ----
        if (c < 63) {
            int nxt = cur ^ 1;
            if (t < 64) {
                float v = dtv * Ah2;
#pragma unroll
                for (int off = 1; off < 64; off <<= 1) {
                    float pv = __shfl_up(v, off, 64);
                    if (t >= off) v += pv;
                }
                float alast = __shfl(v, 63, 64);
                scal[nxt][t] = dtv;
                scal[nxt][64 + t] = v;
                scal[nxt][128 + t] = dtv * fexp2(alast - v);
                scal[nxt][192 + t] = fexp2(v);
            }
            xT[nxt][(sq * 4 + 0) * 72 + sl] = xv.x;
            xT[nxt][(sq * 4 + 1) * 72 + sl] = xv.y;
            xT[nxt][(sq * 4 + 2) * 72 + sl] = xv.z;
            xT[nxt][(sq * 4 + 3) * 72 + sl] = xv.w;
            {
                union { uint4 v; unsigned ww[4]; } q0, q1, q2, q3;
                q0.v = bv0; q1.v = bv1; q2.v = bv2; q3.v = bv3;
                int base = no * 512 + (lq & 1) * 4;
                int lqh = lq >> 1;
#pragma unroll
                for (int j = 0; j < 8; ++j) {
                    unsigned sel = (j & 1) ? 0x07060302u : 0x05040100u;
                    uint2 pk;
                    pk.x = __builtin_amdgcn_perm(q1.ww[j >> 1], q0.ww[j >> 1], sel);
                    pk.y = __builtin_amdgcn_perm(q3.ww[j >> 1], q2.ww[j >> 1], sel);
                    *(uint2*)&BT[nxt][base + j * 64 + ((lqh ^ j) << 3)] = pk;
                }
            }
#pragma unroll
            for (int nt = 0; nt < 2; ++nt) {
                unsigned p01 = cvtpk(sacc[nt][0], sacc[nt][1]);
                unsigned p23 = cvtpk(sacc[nt][2], sacc[nt][3]);
                int colb = 32 * w + 16 * nt + fm;
                Sd[nxt][(fq * 4 + 0) * 136 + colb] = (u16)p01;
                Sd[nxt][(fq * 4 + 1) * 136 + colb] = (u16)(p01 >> 16);
                Sd[nxt][(fq * 4 + 2) * 136 + colb] = (u16)p23;
                Sd[nxt][(fq * 4 + 3) * 136 + colb] = (u16)(p23 >> 16);
            }
        }
        __syncthreads();

        // rotate prefetched operands
#pragma unroll
        for (int kk = 0; kk < 4; ++kk) afr[kk] = afr_n[kk];
#pragma unroll
        for (int kk = 0; kk < 2; ++kk) {
            cbr[kk][0] = cbr_n[kk][0];
            cbr[kk][1] = cbr_n[kk][1];
        }
    }

    // final deferred y store (chunk 63)
    {
        unsigned y01 = cvtpk(ydef[0], ydef[1]);
        unsigned y23 = cvtpk(ydef[2], ydef[3]);
        u16* yp = ybf + (size_t)(b * LTOT + 63 * CHUNK + 16 * w + fq * 4) * D_SSM + pbase + fm;
        yp[0] = (u16)y01;
        yp[D_SSM] = (u16)(y01 >> 16);
        yp[2 * D_SSM] = (u16)y23;
        yp[3 * D_SSM] = (u16)(y23 >> 16);
    }
}

// ---------------- gate (silu(z)) + RMSNorm, in-place on y_bf ----------------
__global__ __launch_bounds__(256) void gate_norm(const u16* __restrict__ zbf,
                                                 const float* __restrict__ normw,
                                                 u16* __restrict__ ybf) {
    int row = blockIdx.x, t = threadIdx.x;
    const uint2* y2 = (const uint2*)(ybf + (size_t)row * D_SSM);
    const uint2* z2 = (const uint2*)(zbf + (size_t)row * D_SSM);
    f4 yg[4];
    float ss = 0.f;
#pragma unroll
    for (int i = 0; i < 4; ++i) {
        int idx = i * 256 + t;
        uint2 yv = y2[idx], zv = z2[idx];
        float ya[4] = {bf2f(yv.x & 0xffffu), bf2f(yv.x >> 16), bf2f(yv.y & 0xffffu), bf2f(yv.y >> 16)};
        float za[4] = {bf2f(zv.x & 0xffffu), bf2f(zv.x >> 16), bf2f(zv.y & 0xffffu), bf2f(zv.y >> 16)};
        f4 g;
#pragma unroll
        for (int k = 0; k < 4; ++k) {
            float sz = za[k] / (1.f + __expf(-za[k]));
            g[k] = ya[k] * sz;
            ss += g[k] * g[k];
        }
        yg[i] = g;
    }
#pragma unroll
    for (int off = 32; off; off >>= 1) ss += __shfl_down(ss, off, 64);
    __shared__ float red[4];
    if ((t & 63) == 0) red[t >> 6] = ss;
    __syncthreads();
    float tot = red[0] + red[1] + red[2] + red[3];
    float scale = rsqrtf(tot / (float)D_SSM + 1e-5f);
    const f4* nw4 = (const f4*)normw;
    uint2* out = (uint2*)(ybf + (size_t)row * D_SSM);
#pragma unroll
    for (int i = 0; i < 4; ++i) {
        int idx = i * 256 + t;
        f4 v = yg[i] * scale * nw4[idx];
        uint2 pk;
        pk.x = pack2(v[0], v[1]);
        pk.y = pack2(v[2], v[3]);
        out[idx] = pk;
    }
}

// ---------------- launch ----------------
extern "C" void kernel_launch(void* const* d_in, const int* in_sizes, int n_in,
                              void* d_out, int out_size, void* d_ws, size_t ws_size,
                              hipStream_t stream) {
    const float* u = (const float*)d_in[0];
    const float* W_in = (const float*)d_in[1];
    const float* conv_w = (const float*)d_in[2];
    const float* conv_b = (const float*)d_in[3];
    const float* dt_bias = (const float*)d_in[4];
    const float* A_log = (const float*)d_in[5];
    const float* Dv = (const float*)d_in[6];
    const float* normw = (const float*)d_in[7];
    const float* W_out = (const float*)d_in[8];
    float* out = (float*)d_out;
    char* ws = (char*)d_ws;

    // workspace layout
    u16* z_bf = (u16*)(ws + 0ULL);              //  8192x4096 bf16 = 67,108,864
    u16* xbcdt = (u16*)(ws + 67108864ULL);      //  8192x4480 bf16 = 73,400,320
    u16* y_bf = xbcdt;                          //  overlay: 8192x4096 bf16
    u16* convO = (u16*)(ws + 140509184ULL);     //  8192x4352 bf16 = 71,303,168
    u16* u_bf = convO;                          //  overlay: 33,554,432
    u16* win_bf = (u16*)(ws + 174063616ULL);    //  overlay: 8704x2048 bf16 = 35,651,584
    u16* wout_bf = convO;                       //  overlay: 16,777,216 (after ssm)
    float* dtp = (float*)(ws + 211812352ULL);   //  8192x64 f32 = 2,097,152
    float* CBb = (float*)(ws + 213909504ULL);   //  128x64x64 f32 = 2,097,152

    tobf16_kernel<<<16384, 256, 0, stream>>>(u, u_bf, 4194304);
    winpad_kernel<<<17408, 256, 0, stream>>>(W_in, win_bf);
    // merged in-projection: N = 8704 (z 4096 | xbc 4608), split output
    gemm256<2><<<dim3(34, 32), 512, 0, stream>>>(u_bf, win_bf, z_bf, xbcdt, 2048, 0, 8576);
    conv_kernel<<<dim3(17, 1024), 256, 0, stream>>>(xbcdt, conv_w, conv_b, convO);
    dt_kernel<<<2048, 256, 0, stream>>>(xbcdt, dt_bias, dtp);
    cb_kernel<<<128, 256, 0, stream>>>(convO, CBb);
    ssm_mfma<<<512, 256, 0, stream>>>(convO, dtp, CBb, A_log, Dv, y_bf);
    tobf16_kernel<<<8192, 256, 0, stream>>>(W_out, wout_bf, 2097152);
    gate_norm<<<8192, 256, 0, stream>>>(z_bf, normw, y_bf);
    gemm256<0><<<dim3(8, 32), 512, 0, stream>>>(y_bf, wout_bf, out, nullptr, 4096, 2048, 2048);
}